// Round 12
// baseline (2498.348 us; speedup 1.0000x reference)
//
#include <hip/hip_runtime.h>

typedef __attribute__((ext_vector_type(8))) short bf16x8;
typedef __attribute__((ext_vector_type(2))) float f32x2;
typedef __attribute__((ext_vector_type(4))) float f32x4;
typedef __attribute__((ext_vector_type(4))) unsigned short u16x4;
typedef __attribute__((ext_vector_type(8))) unsigned short u16x8;

__device__ __forceinline__ float bf2f(unsigned short u) {
    union { unsigned int i; float f; } v; v.i = ((unsigned int)u) << 16; return v.f;
}
__device__ __forceinline__ unsigned short f2bf(float f) {
    union { float f; unsigned int i; } v; v.f = f;
    unsigned int b = v.i;
    b += 0x7FFFu + ((b >> 16) & 1u);   // round-to-nearest-even
    return (unsigned short)(b >> 16);
}
__device__ __forceinline__ unsigned char f2f8(float f) {
    int p = __builtin_amdgcn_cvt_pk_fp8_f32(f, f, 0, false);
    return (unsigned char)(p & 0xFF);
}
// decode meta word: src = m >> 8, w = fp8(m & 0xFF) * 2^-5
__device__ __forceinline__ float meta_w(unsigned int m) {
    f32x2 lo = __builtin_amdgcn_cvt_pk_f32_fp8(m & 0xFFu, false);
    return lo[0] * 0.03125f;
}

// ---------------- fused weight transpose: W,SW [L][K][256] -> Wf[L][256][2*Kp] bf16 ----------------
__global__ __launch_bounds__(256) void transpose_fused_kernel(
    const float* __restrict__ W, const float* __restrict__ SW,
    unsigned short* __restrict__ Wf, int K, int Kp, int L)
{
    long long total = (long long)L * 256 * 2 * Kp;
    long long idx = (long long)blockIdx.x * blockDim.x + threadIdx.x;
    const long long stride = (long long)gridDim.x * blockDim.x;
    for (; idx < total; idx += stride) {
        int l = (int)(idx / ((long long)256 * 2 * Kp));
        long long rem = idx - (long long)l * 256 * 2 * Kp;
        int c = (int)(rem / (2 * Kp));
        int kk = (int)(rem - (long long)c * 2 * Kp);
        const float* src = (kk < Kp) ? W : SW;
        int k = (kk < Kp) ? kk : kk - Kp;
        float v = (k < K) ? src[((size_t)l * K + k) * 256 + c] : 0.f;
        Wf[idx] = f2bf(v);
    }
}

// ---------------- Wc[1268][40] fp32 -> Wcb[48][1280] bf16 ----------------
__global__ __launch_bounds__(256) void transpose_wc_kernel(
    const float* __restrict__ Wc, unsigned short* __restrict__ Wcb)
{
    int idx = blockIdx.x * blockDim.x + threadIdx.x;
    if (idx >= 48 * 1280) return;
    int c = idx / 1280;
    int kk = idx - c * 1280;
    int src = -1;
    if (kk < 512)       { if (kk < 500) src = kk; }
    else if (kk < 768)  src = 500 + (kk - 512);
    else if (kk < 1024) src = 756 + (kk - 768);
    else                src = 1012 + (kk - 1024);
    float v = (c < 40 && src >= 0) ? Wc[(size_t)src * 40 + c] : 0.f;
    Wcb[idx] = f2bf(v);
}

// ---------------- x -> bf16 [N][512] AND fp8 [N][512] ----------------
__global__ __launch_bounds__(256) void cvtx_kernel(
    const float* __restrict__ X, unsigned short* __restrict__ Xb,
    unsigned char* __restrict__ X8, int N)
{
    long long total = (long long)N * 64;
    long long idx = (long long)blockIdx.x * blockDim.x + threadIdx.x;
    const long long stride = (long long)gridDim.x * blockDim.x;
    for (; idx < total; idx += stride) {
        long long row = idx >> 6;
        int g = (int)(idx & 63);
        int k0 = g * 8;
        float v[8];
        if (k0 + 8 <= 500) {
            float4 q0 = *reinterpret_cast<const float4*>(X + row * 500 + k0);
            float4 q1 = *reinterpret_cast<const float4*>(X + row * 500 + k0 + 4);
            v[0] = q0.x; v[1] = q0.y; v[2] = q0.z; v[3] = q0.w;
            v[4] = q1.x; v[5] = q1.y; v[6] = q1.z; v[7] = q1.w;
        } else {
#pragma unroll
            for (int j = 0; j < 8; ++j) v[j] = (k0 + j < 500) ? X[row * 500 + k0 + j] : 0.f;
        }
        u16x8 o;
#pragma unroll
        for (int j = 0; j < 8; ++j) o[j] = f2bf(v[j]);
        *reinterpret_cast<u16x8*>(Xb + row * 512 + k0) = o;
        int p0 = 0, p1 = 0;
        p0 = __builtin_amdgcn_cvt_pk_fp8_f32(v[0], v[1], p0, false);
        p0 = __builtin_amdgcn_cvt_pk_fp8_f32(v[2], v[3], p0, true);
        p1 = __builtin_amdgcn_cvt_pk_fp8_f32(v[4], v[5], p1, false);
        p1 = __builtin_amdgcn_cvt_pk_fp8_f32(v[6], v[7], p1, true);
        uint2 pk = make_uint2((unsigned int)p0, (unsigned int)p1);
        *reinterpret_cast<uint2*>(X8 + row * 512 + k0) = pk;
    }
}

// ---------------- CSR build ----------------
__global__ __launch_bounds__(256) void hist_kernel(
    const int* __restrict__ edst, int* __restrict__ cnt, int n_edges)
{
    int idx = blockIdx.x * blockDim.x + threadIdx.x;
    const int stride = gridDim.x * blockDim.x;
    for (; idx < n_edges; idx += stride) atomicAdd(&cnt[edst[idx]], 1);
}

__global__ __launch_bounds__(256) void scan1_kernel(
    const int* __restrict__ cnt, int* __restrict__ excl,
    int* __restrict__ blocksums, int n)
{
    __shared__ int s[256];
    const int tid = threadIdx.x;
    const int i = blockIdx.x * 256 + tid;
    int v = (i < n) ? cnt[i] : 0;
    s[tid] = v;
    __syncthreads();
#pragma unroll
    for (int off = 1; off < 256; off <<= 1) {
        int t = s[tid];
        if (tid >= off) t += s[tid - off];
        __syncthreads();
        s[tid] = t;
        __syncthreads();
    }
    if (i < n) excl[i] = s[tid] - v;
    if (tid == 255) blocksums[blockIdx.x] = s[255];
}

__global__ __launch_bounds__(512) void scan2_kernel(int* __restrict__ blocksums, int nb)
{
    __shared__ int s[512];
    const int tid = threadIdx.x;
    int v = (tid < nb) ? blocksums[tid] : 0;
    s[tid] = v;
    __syncthreads();
#pragma unroll
    for (int off = 1; off < 512; off <<= 1) {
        int t = s[tid];
        if (tid >= off) t += s[tid - off];
        __syncthreads();
        s[tid] = t;
        __syncthreads();
    }
    if (tid < nb) blocksums[tid] = s[tid] - v;
}

// also initializes per-bucket heads (bucket = node >> 7)
__global__ __launch_bounds__(256) void scan3_kernel(
    const int* __restrict__ excl, const int* __restrict__ blocksums,
    int* __restrict__ row_ptr, int* __restrict__ heads,
    int* __restrict__ bheads, int n, int n_edges)
{
    const int i = blockIdx.x * 256 + threadIdx.x;
    if (i < n) {
        int v = excl[i] + blocksums[i >> 8];
        row_ptr[i] = v;
        heads[i] = v;
        if ((i & 127) == 0) bheads[i >> 7] = v;
    }
    if (i == 0) row_ptr[n] = n_edges;
}

// ---------------- two-phase scatter: bucket partition then local placement ----------------
// Phase 1: stream edges -> (dst, metaword) into bucket region (write lines L2-merged).
__global__ __launch_bounds__(256) void part1_kernel(
    const int* __restrict__ esrc, const int* __restrict__ edst,
    const float* __restrict__ ew, int* __restrict__ bheads,
    uint2* __restrict__ tmp, int n_edges)
{
    int idx = blockIdx.x * blockDim.x + threadIdx.x;
    const int stride = gridDim.x * blockDim.x;
    for (; idx < n_edges; idx += stride) {
        int d = edst[idx];
        unsigned int m = ((unsigned int)esrc[idx] << 8) | f2f8(ew[idx] * 32.0f);
        int pos = atomicAdd(&bheads[d >> 7], 1);
        tmp[pos] = make_uint2((unsigned int)d, m);
    }
}

// Phase 2: one block per bucket; writes confined to ~16KB window (L2-resident).
__global__ __launch_bounds__(256) void part2_kernel(
    const int* __restrict__ row_ptr, const uint2* __restrict__ tmp,
    int* __restrict__ heads, unsigned int* __restrict__ meta, int N)
{
    const int b = blockIdx.x;
    const int nbeg = b << 7;
    int nend = nbeg + 128; if (nend > N) nend = N;
    const int beg = row_ptr[nbeg];
    const int end = row_ptr[nend];
    for (int e = beg + threadIdx.x; e < end; e += blockDim.x) {
        uint2 t = tmp[e];
        int pos = atomicAdd(&heads[t.x], 1);
        meta[pos] = t.y;
    }
}

// ---------------- SpMM 256-wide, fp8 source, on-the-fly BN+ReLU ----------------
__global__ __launch_bounds__(256) void spmm256bn_kernel(
    const int* __restrict__ row_ptr, const unsigned int* __restrict__ meta,
    const unsigned char* __restrict__ S8, const float* __restrict__ kp,
    unsigned short* __restrict__ O, int N)
{
    const int wave = threadIdx.x >> 6;
    const int lane = threadIdx.x & 63;
    int node = blockIdx.x * 4 + wave;
    if (node >= N) return;
    node = __builtin_amdgcn_readfirstlane(node);
    const int beg = row_ptr[node];
    const int end = row_ptr[node + 1];
    const f32x4 sc = *reinterpret_cast<const f32x4*>(kp + lane * 4);
    const f32x4 sh = *reinterpret_cast<const f32x4*>(kp + 256 + lane * 4);
    float a0 = 0.f, a1 = 0.f, a2 = 0.f, a3 = 0.f;

    int e = beg;
    for (; e + 12 <= end; e += 12) {
        unsigned int m[12];
#pragma unroll
        for (int j = 0; j < 12; ++j) m[j] = meta[e + j];
        unsigned int v[12];
#pragma unroll
        for (int j = 0; j < 12; ++j)
            v[j] = *reinterpret_cast<const unsigned int*>(S8 + (size_t)(m[j] >> 8) * 256 + lane * 4);
#pragma unroll
        for (int j = 0; j < 12; ++j) {
            float w = meta_w(m[j]);
            f32x2 lo = __builtin_amdgcn_cvt_pk_f32_fp8(v[j], false);
            f32x2 hi = __builtin_amdgcn_cvt_pk_f32_fp8(v[j], true);
            a0 = fmaf(w, fmaxf(fmaf(lo[0], sc[0], sh[0]), 0.f), a0);
            a1 = fmaf(w, fmaxf(fmaf(lo[1], sc[1], sh[1]), 0.f), a1);
            a2 = fmaf(w, fmaxf(fmaf(hi[0], sc[2], sh[2]), 0.f), a2);
            a3 = fmaf(w, fmaxf(fmaf(hi[1], sc[3], sh[3]), 0.f), a3);
        }
    }
    for (; e < end; ++e) {
        unsigned int m = meta[e];
        float w = meta_w(m);
        unsigned int v = *reinterpret_cast<const unsigned int*>(S8 + (size_t)(m >> 8) * 256 + lane * 4);
        f32x2 lo = __builtin_amdgcn_cvt_pk_f32_fp8(v, false);
        f32x2 hi = __builtin_amdgcn_cvt_pk_f32_fp8(v, true);
        a0 = fmaf(w, fmaxf(fmaf(lo[0], sc[0], sh[0]), 0.f), a0);
        a1 = fmaf(w, fmaxf(fmaf(lo[1], sc[1], sh[1]), 0.f), a1);
        a2 = fmaf(w, fmaxf(fmaf(hi[0], sc[2], sh[2]), 0.f), a2);
        a3 = fmaf(w, fmaxf(fmaf(hi[1], sc[3], sh[3]), 0.f), a3);
    }
    u16x4 o;
    o[0] = f2bf(a0); o[1] = f2bf(a1); o[2] = f2bf(a2); o[3] = f2bf(a3);
    *reinterpret_cast<u16x4*>(O + (size_t)node * 256 + lane * 4) = o;
}

// ---------------- fused dual SpMM 256-wide: one edge walk, two fp8 sources ----------------
__global__ __launch_bounds__(256) void spmm256x2bn_kernel(
    const int* __restrict__ row_ptr, const unsigned int* __restrict__ meta,
    const unsigned char* __restrict__ S8a, const float* __restrict__ kpa,
    const unsigned char* __restrict__ S8b, const float* __restrict__ kpb,
    unsigned short* __restrict__ Oa, unsigned short* __restrict__ Ob, int N)
{
    const int wave = threadIdx.x >> 6;
    const int lane = threadIdx.x & 63;
    int node = blockIdx.x * 4 + wave;
    if (node >= N) return;
    node = __builtin_amdgcn_readfirstlane(node);
    const int beg = row_ptr[node];
    const int end = row_ptr[node + 1];
    const f32x4 sca = *reinterpret_cast<const f32x4*>(kpa + lane * 4);
    const f32x4 sha = *reinterpret_cast<const f32x4*>(kpa + 256 + lane * 4);
    const f32x4 scb = *reinterpret_cast<const f32x4*>(kpb + lane * 4);
    const f32x4 shb = *reinterpret_cast<const f32x4*>(kpb + 256 + lane * 4);
    float a0 = 0.f, a1 = 0.f, a2 = 0.f, a3 = 0.f;
    float b0 = 0.f, b1 = 0.f, b2 = 0.f, b3 = 0.f;

    int e = beg;
    for (; e + 8 <= end; e += 8) {
        unsigned int m[8];
#pragma unroll
        for (int j = 0; j < 8; ++j) m[j] = meta[e + j];
        unsigned int va[8], vb[8];
#pragma unroll
        for (int j = 0; j < 8; ++j) {
            size_t off = (size_t)(m[j] >> 8) * 256 + lane * 4;
            va[j] = *reinterpret_cast<const unsigned int*>(S8a + off);
            vb[j] = *reinterpret_cast<const unsigned int*>(S8b + off);
        }
#pragma unroll
        for (int j = 0; j < 8; ++j) {
            float w = meta_w(m[j]);
            f32x2 alo = __builtin_amdgcn_cvt_pk_f32_fp8(va[j], false);
            f32x2 ahi = __builtin_amdgcn_cvt_pk_f32_fp8(va[j], true);
            f32x2 blo = __builtin_amdgcn_cvt_pk_f32_fp8(vb[j], false);
            f32x2 bhi = __builtin_amdgcn_cvt_pk_f32_fp8(vb[j], true);
            a0 = fmaf(w, fmaxf(fmaf(alo[0], sca[0], sha[0]), 0.f), a0);
            a1 = fmaf(w, fmaxf(fmaf(alo[1], sca[1], sha[1]), 0.f), a1);
            a2 = fmaf(w, fmaxf(fmaf(ahi[0], sca[2], sha[2]), 0.f), a2);
            a3 = fmaf(w, fmaxf(fmaf(ahi[1], sca[3], sha[3]), 0.f), a3);
            b0 = fmaf(w, fmaxf(fmaf(blo[0], scb[0], shb[0]), 0.f), b0);
            b1 = fmaf(w, fmaxf(fmaf(blo[1], scb[1], shb[1]), 0.f), b1);
            b2 = fmaf(w, fmaxf(fmaf(bhi[0], scb[2], shb[2]), 0.f), b2);
            b3 = fmaf(w, fmaxf(fmaf(bhi[1], scb[3], shb[3]), 0.f), b3);
        }
    }
    for (; e < end; ++e) {
        unsigned int m = meta[e];
        float w = meta_w(m);
        size_t off = (size_t)(m >> 8) * 256 + lane * 4;
        unsigned int va = *reinterpret_cast<const unsigned int*>(S8a + off);
        unsigned int vb = *reinterpret_cast<const unsigned int*>(S8b + off);
        f32x2 alo = __builtin_amdgcn_cvt_pk_f32_fp8(va, false);
        f32x2 ahi = __builtin_amdgcn_cvt_pk_f32_fp8(va, true);
        f32x2 blo = __builtin_amdgcn_cvt_pk_f32_fp8(vb, false);
        f32x2 bhi = __builtin_amdgcn_cvt_pk_f32_fp8(vb, true);
        a0 = fmaf(w, fmaxf(fmaf(alo[0], sca[0], sha[0]), 0.f), a0);
        a1 = fmaf(w, fmaxf(fmaf(alo[1], sca[1], sha[1]), 0.f), a1);
        a2 = fmaf(w, fmaxf(fmaf(ahi[0], sca[2], sha[2]), 0.f), a2);
        a3 = fmaf(w, fmaxf(fmaf(ahi[1], sca[3], sha[3]), 0.f), a3);
        b0 = fmaf(w, fmaxf(fmaf(blo[0], scb[0], shb[0]), 0.f), b0);
        b1 = fmaf(w, fmaxf(fmaf(blo[1], scb[1], shb[1]), 0.f), b1);
        b2 = fmaf(w, fmaxf(fmaf(bhi[0], scb[2], shb[2]), 0.f), b2);
        b3 = fmaf(w, fmaxf(fmaf(bhi[1], scb[3], shb[3]), 0.f), b3);
    }
    u16x4 oa, ob;
    oa[0] = f2bf(a0); oa[1] = f2bf(a1); oa[2] = f2bf(a2); oa[3] = f2bf(a3);
    ob[0] = f2bf(b0); ob[1] = f2bf(b1); ob[2] = f2bf(b2); ob[3] = f2bf(b3);
    *reinterpret_cast<u16x4*>(Oa + (size_t)node * 256 + lane * 4) = oa;
    *reinterpret_cast<u16x4*>(Ob + (size_t)node * 256 + lane * 4) = ob;
}

// ---------------- SpMM 512-wide, fp8 source: TWO waves per node, 8-deep ----------------
__global__ __launch_bounds__(512) void spmm512_kernel(
    const int* __restrict__ row_ptr, const unsigned int* __restrict__ meta,
    const unsigned char* __restrict__ S8, unsigned short* __restrict__ O, int N)
{
    const int wv = threadIdx.x >> 6;
    const int lane = threadIdx.x & 63;
    const int half = wv & 1;
    int node = blockIdx.x * 4 + (wv >> 1);
    if (node >= N) return;
    node = __builtin_amdgcn_readfirstlane(node);
    const int beg = row_ptr[node];
    const int end = row_ptr[node + 1];
    const int coff = half * 256 + lane * 4;
    float a0 = 0.f, a1 = 0.f, a2 = 0.f, a3 = 0.f;

    int e = beg;
    for (; e + 8 <= end; e += 8) {
        unsigned int m[8];
#pragma unroll
        for (int j = 0; j < 8; ++j) m[j] = meta[e + j];
        unsigned int v[8];
#pragma unroll
        for (int j = 0; j < 8; ++j)
            v[j] = *reinterpret_cast<const unsigned int*>(S8 + (size_t)(m[j] >> 8) * 512 + coff);
#pragma unroll
        for (int j = 0; j < 8; ++j) {
            float w = meta_w(m[j]);
            f32x2 lo = __builtin_amdgcn_cvt_pk_f32_fp8(v[j], false);
            f32x2 hi = __builtin_amdgcn_cvt_pk_f32_fp8(v[j], true);
            a0 = fmaf(w, lo[0], a0);
            a1 = fmaf(w, lo[1], a1);
            a2 = fmaf(w, hi[0], a2);
            a3 = fmaf(w, hi[1], a3);
        }
    }
    for (; e < end; ++e) {
        unsigned int m = meta[e];
        float w = meta_w(m);
        unsigned int v = *reinterpret_cast<const unsigned int*>(S8 + (size_t)(m >> 8) * 512 + coff);
        f32x2 lo = __builtin_amdgcn_cvt_pk_f32_fp8(v, false);
        f32x2 hi = __builtin_amdgcn_cvt_pk_f32_fp8(v, true);
        a0 = fmaf(w, lo[0], a0);
        a1 = fmaf(w, lo[1], a1);
        a2 = fmaf(w, hi[0], a2);
        a3 = fmaf(w, hi[1], a3);
    }
    u16x4 o;
    o[0] = f2bf(a0); o[1] = f2bf(a1); o[2] = f2bf(a2); o[3] = f2bf(a3);
    *reinterpret_cast<u16x4*>(O + (size_t)node * 512 + coff) = o;
}

// ---------------- LDS-staged MFMA GEMM ----------------
template<int K1, int K2, bool BN2>
__global__ __launch_bounds__(256) void gemm_lds_kernel(
    const unsigned short* __restrict__ A1, const unsigned short* __restrict__ A2,
    const float* __restrict__ kp, const unsigned short* __restrict__ Btf,
    const float* __restrict__ bias, unsigned short* __restrict__ Cout,
    unsigned char* __restrict__ C8, float* __restrict__ stats, int N)
{
    constexpr int KT = K1 + K2;
    __shared__ unsigned short Atile[128 * 64];
    __shared__ unsigned short Btile[128 * 64];

    const int lane = threadIdx.x & 63;
    const int wave = threadIdx.x >> 6;
    const int l16 = lane & 15;
    const int khi = lane >> 4;
    const int wm = wave >> 1;
    const int wn = wave & 1;
    const long long bm = (long long)blockIdx.x * 128;
    const int col0 = blockIdx.y * 128;

    const int srow8 = lane >> 3;
    const int sc16 = lane & 7;

    f32x4 acc[4][4];
#pragma unroll
    for (int m = 0; m < 4; ++m)
#pragma unroll
        for (int n = 0; n < 4; ++n) acc[m][n] = (f32x4){0.f, 0.f, 0.f, 0.f};

    for (int k0 = 0; k0 < KT; k0 += 64) {
        const unsigned short* Aseg;
        int koff, astr;
        if (k0 < K1) { Aseg = A1; koff = k0; astr = K1; }
        else         { Aseg = A2; koff = k0 - K1; astr = K2; }
        const bool bnseg = BN2 && (k0 >= K1);

        u16x8 av[4], bv[4];
        int rloc[4];
#pragma unroll
        for (int i = 0; i < 4; ++i) {
            int r = wave * 32 + i * 8 + srow8;
            rloc[i] = r;
            long long gr = bm + r;
            if (gr >= N) gr = N - 1;
            av[i] = *reinterpret_cast<const u16x8*>(Aseg + (size_t)gr * astr + koff + sc16 * 8);
            bv[i] = *reinterpret_cast<const u16x8*>(Btf + (size_t)(col0 + r) * KT + k0 + sc16 * 8);
        }
        __syncthreads();
#pragma unroll
        for (int i = 0; i < 4; ++i) {
            int r = rloc[i];
            int cw = (sc16 ^ (r & 7)) * 8;
            *reinterpret_cast<u16x8*>(&Atile[r * 64 + cw]) = av[i];
            *reinterpret_cast<u16x8*>(&Btile[r * 64 + cw]) = bv[i];
        }
        __syncthreads();

#pragma unroll
        for (int kk = 0; kk < 2; ++kk) {
            const int kc = kk * 4 + khi;
            bf16x8 a[4], b[4];
#pragma unroll
            for (int m = 0; m < 4; ++m) {
                int ra = wm * 64 + m * 16 + l16;
                a[m] = *reinterpret_cast<const bf16x8*>(&Atile[ra * 64 + ((kc ^ (ra & 7)) * 8)]);
            }
            if (bnseg) {
                int ch = (k0 - K1) + kk * 32 + khi * 8;
                f32x4 s0 = *reinterpret_cast<const f32x4*>(kp + ch);
                f32x4 s1 = *reinterpret_cast<const f32x4*>(kp + ch + 4);
                f32x4 t0 = *reinterpret_cast<const f32x4*>(kp + 256 + ch);
                f32x4 t1 = *reinterpret_cast<const f32x4*>(kp + 256 + ch + 4);
#pragma unroll
                for (int m = 0; m < 4; ++m) {
                    u16x8 raw;
                    __builtin_memcpy(&raw, &a[m], 16);
                    u16x8 ov;
#pragma unroll
                    for (int j = 0; j < 4; ++j) {
                        ov[j]     = f2bf(fmaxf(fmaf(bf2f(raw[j]),     s0[j], t0[j]), 0.f));
                        ov[4 + j] = f2bf(fmaxf(fmaf(bf2f(raw[4 + j]), s1[j], t1[j]), 0.f));
                    }
                    __builtin_memcpy(&a[m], &ov, 16);
                }
            }
#pragma unroll
            for (int n = 0; n < 4; ++n) {
                int rb = wn * 64 + n * 16 + l16;
                b[n] = *reinterpret_cast<const bf16x8*>(&Btile[rb * 64 + ((kc ^ (rb & 7)) * 8)]);
            }
#pragma unroll
            for (int m = 0; m < 4; ++m)
#pragma unroll
                for (int n = 0; n < 4; ++n)
                    acc[m][n] = __builtin_amdgcn_mfma_f32_16x16x32_bf16(a[m], b[n], acc[m][n], 0, 0, 0);
        }
    }

    float bs[4];
#pragma unroll
    for (int n = 0; n < 4; ++n) bs[n] = bias[col0 + wn * 64 + n * 16 + l16];

    float s[4], s2[4];
#pragma unroll
    for (int n = 0; n < 4; ++n) { s[n] = 0.f; s2[n] = 0.f; }

#pragma unroll
    for (int m = 0; m < 4; ++m)
#pragma unroll
        for (int r = 0; r < 4; ++r) {
            long long grow = bm + wm * 64 + m * 16 + khi * 4 + r;
            if (grow >= N) continue;
#pragma unroll
            for (int n = 0; n < 4; ++n) {
                int gcol = col0 + wn * 64 + n * 16 + l16;
                float v = acc[m][n][r] + bs[n];
                Cout[grow * 256 + gcol] = f2bf(v);
                if (C8) C8[grow * 256 + gcol] = f2f8(v);
                s[n] += v;
                s2[n] = fmaf(v, v, s2[n]);
            }
        }

#pragma unroll
    for (int n = 0; n < 4; ++n) {
        float a = s[n], b2 = s2[n];
        a += __shfl_xor(a, 16); a += __shfl_xor(a, 32);
        b2 += __shfl_xor(b2, 16); b2 += __shfl_xor(b2, 32);
        if (khi == 0) {
            int c = col0 + wn * 64 + n * 16 + l16;
            atomicAdd(&stats[c], a);
            atomicAdd(&stats[256 + c], b2);
        }
    }
}

// ---------------- BN finalize ----------------
__global__ __launch_bounds__(256) void bn_finalize_kernel(
    const float* __restrict__ sums, const float* __restrict__ g,
    const float* __restrict__ be, float* __restrict__ kp, int N)
{
    const int c = threadIdx.x;
    float invN = 1.f / (float)N;
    float mean = sums[c] * invN;
    float var = sums[256 + c] * invN - mean * mean;
    float inv = rsqrtf(var + 1e-5f);
    float sc = g[c] * inv;
    kp[c] = sc;
    kp[256 + c] = be[c] - sc * mean;
}

__global__ __launch_bounds__(256) void bn_finalize3_kernel(
    float* __restrict__ stats, const float* __restrict__ g,
    const float* __restrict__ be, int N)
{
    const int l = blockIdx.x;
    const int c = threadIdx.x;
    float* st = stats + (size_t)l * 1024;
    float invN = 1.f / (float)N;
    float mean = st[c] * invN;
    float var = st[256 + c] * invN - mean * mean;
    float inv = rsqrtf(var + 1e-5f);
    float sc = g[l * 256 + c] * inv;
    st[512 + c] = sc;
    st[768 + c] = be[l * 256 + c] - sc * mean;
}

// ---------------- final MFMA outproj ----------------
template<int KS, bool BN>
__device__ __forceinline__ void outproj_seg(
    const unsigned short* __restrict__ seg, const float* __restrict__ kp,
    const unsigned short* __restrict__ Wcb, int bOff,
    long long r0, long long r1, int l16, int khi, f32x4 acc[2][3])
{
    const unsigned short* a0p = seg + (size_t)r0 * KS + khi * 8;
    const unsigned short* a1p = seg + (size_t)r1 * KS + khi * 8;
#pragma unroll
    for (int k0 = 0; k0 < KS; k0 += 32) {
        bf16x8 a[2];
        a[0] = *reinterpret_cast<const bf16x8*>(a0p + k0);
        a[1] = *reinterpret_cast<const bf16x8*>(a1p + k0);
        if (BN) {
            int ch0 = k0 + khi * 8;
            f32x4 s0 = *reinterpret_cast<const f32x4*>(kp + ch0);
            f32x4 s1 = *reinterpret_cast<const f32x4*>(kp + ch0 + 4);
            f32x4 t0 = *reinterpret_cast<const f32x4*>(kp + 256 + ch0);
            f32x4 t1 = *reinterpret_cast<const f32x4*>(kp + 256 + ch0 + 4);
#pragma unroll
            for (int m = 0; m < 2; ++m) {
                u16x8 raw;
                __builtin_memcpy(&raw, &a[m], 16);
                u16x8 ov;
#pragma unroll
                for (int j = 0; j < 4; ++j) {
                    ov[j]     = f2bf(fmaxf(fmaf(bf2f(raw[j]),     s0[j], t0[j]), 0.f));
                    ov[4 + j] = f2bf(fmaxf(fmaf(bf2f(raw[4 + j]), s1[j], t1[j]), 0.f));
                }
                __builtin_memcpy(&a[m], &ov, 16);
            }
        }
        bf16x8 b[3];
#pragma unroll
        for (int nt = 0; nt < 3; ++nt)
            b[nt] = *reinterpret_cast<const bf16x8*>(Wcb + (size_t)(nt * 16 + l16) * 1280 + bOff + k0 + khi * 8);
#pragma unroll
        for (int m = 0; m < 2; ++m)
#pragma unroll
            for (int nt = 0; nt < 3; ++nt)
                acc[m][nt] = __builtin_amdgcn_mfma_f32_16x16x32_bf16(a[m], b[nt], acc[m][nt], 0, 0, 0);
    }
}

__global__ __launch_bounds__(256) void outproj_mfma_kernel(
    const unsigned short* __restrict__ x_bf,
    const unsigned short* __restrict__ F0, const float* __restrict__ kp0,
    const unsigned short* __restrict__ F1, const float* __restrict__ kp1,
    const unsigned short* __restrict__ F2, const float* __restrict__ kp2,
    const unsigned short* __restrict__ Wcb, const float* __restrict__ bc,
    float* __restrict__ out, int N)
{
    const int lane = threadIdx.x & 63;
    const int wave = threadIdx.x >> 6;
    const int l16 = lane & 15;
    const int khi = lane >> 4;
    const long long bm = (long long)blockIdx.x * 128 + wave * 32;

    long long r0 = bm + l16;        if (r0 >= N) r0 = 0;
    long long r1 = bm + 16 + l16;   if (r1 >= N) r1 = 0;

    f32x4 acc[2][3];
#pragma unroll
    for (int m = 0; m < 2; ++m)
#pragma unroll
        for (int nt = 0; nt < 3; ++nt) acc[m][nt] = (f32x4){0.f, 0.f, 0.f, 0.f};

    outproj_seg<512, false>(x_bf, nullptr, Wcb, 0,    r0, r1, l16, khi, acc);
    outproj_seg<256, true >(F0,   kp0,     Wcb, 512,  r0, r1, l16, khi, acc);
    outproj_seg<256, true >(F1,   kp1,     Wcb, 768,  r0, r1, l16, khi, acc);
    outproj_seg<256, true >(F2,   kp2,     Wcb, 1024, r0, r1, l16, khi, acc);

#pragma unroll
    for (int m = 0; m < 2; ++m)
#pragma unroll
        for (int nt = 0; nt < 3; ++nt)
#pragma unroll
            for (int r = 0; r < 4; ++r) {
                long long grow = bm + m * 16 + khi * 4 + r;
                int gcol = nt * 16 + l16;
                if (grow < N && gcol < 40)
                    out[grow * 40 + gcol] = acc[m][nt][r] + bc[gcol];
            }
}

// ---------------- host-side orchestration ----------------
extern "C" void kernel_launch(void* const* d_in, const int* in_sizes, int n_in,
                              void* d_out, int out_size, void* d_ws, size_t ws_size,
                              hipStream_t stream)
{
    const float* x      = (const float*)d_in[0];
    const int*   esrc   = (const int*)d_in[1];
    const int*   edst   = (const int*)d_in[2];
    const float* ew     = (const float*)d_in[3];
    const float* W_in   = (const float*)d_in[4];
    const float* SW_in  = (const float*)d_in[5];
    const float* b_in   = (const float*)d_in[6];
    const float* g_in   = (const float*)d_in[7];
    const float* be_in  = (const float*)d_in[8];
    const float* W_h    = (const float*)d_in[9];
    const float* SW_h   = (const float*)d_in[10];
    const float* b_h    = (const float*)d_in[11];
    const float* g_h    = (const float*)d_in[12];
    const float* be_h   = (const float*)d_in[13];
    const float* Wc     = (const float*)d_in[14];
    const float* bc     = (const float*)d_in[15];
    float* out = (float*)d_out;

    const int N = in_sizes[0] / 500;      // 100000
    const int n_edges = in_sizes[1];      // 3200000
    const int nb = (N + 255) / 256;
    const int nbuckets = (N + 127) / 128;

    // ---- workspace layout ----
    char* p = (char*)d_ws;
    unsigned short* x_bf = (unsigned short*)p; p += (size_t)N * 512 * 2;
    unsigned short* Xa   = (unsigned short*)p; p += (size_t)N * 512 * 2;   // F2 aliases
    unsigned short* Ha   = (unsigned short*)p; p += (size_t)N * 256 * 2;
    unsigned short* Ha2  = (unsigned short*)p; p += (size_t)N * 256 * 2;
    unsigned short* G1   = (unsigned short*)p; p += (size_t)N * 256 * 2;   // H2 aliases
    unsigned short* G2   = (unsigned short*)p; p += (size_t)N * 256 * 2;
    unsigned short* F0   = (unsigned short*)p; p += (size_t)N * 256 * 2;
    unsigned short* F1   = (unsigned short*)p; p += (size_t)N * 256 * 2;
    unsigned short* H2   = G1;
    unsigned short* F2   = Xa;
    uint2* tmp = (uint2*)Ha;        // alias: tmp dead before Ha's first write
    unsigned char* x_f8  = (unsigned char*)p; p += (size_t)N * 512;
    unsigned char* G1_f8 = (unsigned char*)p; p += (size_t)N * 256;
    unsigned char* G2_f8 = (unsigned char*)p; p += (size_t)N * 256;
    unsigned char* H2_f8 = G1_f8;   // alias: G1_f8 dead after dual spmm
    unsigned short* Wf_in = (unsigned short*)p; p += (size_t)3 * 256 * 1024 * 2;
    unsigned short* Wf_h  = (unsigned short*)p; p += (size_t)3 * 256 * 512 * 2;
    unsigned short* Wcb   = (unsigned short*)p; p += (size_t)48 * 1280 * 2;
    float* stats = (float*)p; p += (size_t)6 * 1024 * 4;
    int* cnt     = (int*)p; p += (size_t)N * 4;
    int* excl    = (int*)p; p += (size_t)N * 4;
    int* blocksums = (int*)p; p += 2048 * 4;
    int* bheads  = (int*)p; p += 2048 * 4;
    int* row_ptr = (int*)p; p += (size_t)(N + 1) * 4 + 4;
    int* heads   = (int*)p; p += (size_t)N * 4;
    unsigned int* meta = (unsigned int*)p;

    // ---- preprocessing ----
    hipMemsetAsync(stats, 0, (size_t)6 * 1024 * sizeof(float) + (size_t)N * sizeof(int), stream);
    hipLaunchKernelGGL(transpose_fused_kernel, dim3(2048), dim3(256), 0, stream,
                       W_in, SW_in, Wf_in, 500, 512, 3);
    hipLaunchKernelGGL(transpose_fused_kernel, dim3(1024), dim3(256), 0, stream,
                       W_h, SW_h, Wf_h, 256, 256, 3);
    hipLaunchKernelGGL(transpose_wc_kernel, dim3(240), dim3(256), 0, stream, Wc, Wcb);

    hipLaunchKernelGGL(hist_kernel, dim3(4096), dim3(256), 0, stream, edst, cnt, n_edges);
    hipLaunchKernelGGL(scan1_kernel, dim3(nb), dim3(256), 0, stream, cnt, excl, blocksums, N);
    hipLaunchKernelGGL(scan2_kernel, dim3(1), dim3(512), 0, stream, blocksums, nb);
    hipLaunchKernelGGL(scan3_kernel, dim3(nb), dim3(256), 0, stream,
                       excl, blocksums, row_ptr, heads, bheads, N, n_edges);
    // two-phase scatter
    hipLaunchKernelGGL(part1_kernel, dim3(4096), dim3(256), 0, stream,
                       esrc, edst, ew, bheads, tmp, n_edges);
    hipLaunchKernelGGL(part2_kernel, dim3(nbuckets), dim3(256), 0, stream,
                       row_ptr, tmp, heads, meta, N);

    hipLaunchKernelGGL(cvtx_kernel, dim3(4096), dim3(256), 0, stream, x, x_bf, x_f8, N);

    hipLaunchKernelGGL(spmm512_kernel, dim3((N + 3) / 4), dim3(512), 0, stream,
                       row_ptr, meta, x_f8, Xa, N);

    dim3 blk(256);
    dim3 ggrid2((N + 127) / 128, 2);
    dim3 ogrid((N + 127) / 128);
    dim3 sgrid((N + 3) / 4);

    // ---- three input-layer GEMMs ----
    hipLaunchKernelGGL((gemm_lds_kernel<512, 512, false>), ggrid2, blk, 0, stream,
                       Xa, x_bf, (const float*)nullptr, Wf_in, b_in,
                       F0, (unsigned char*)nullptr, stats + 0 * 1024, N);
    hipLaunchKernelGGL((gemm_lds_kernel<512, 512, false>), ggrid2, blk, 0, stream,
                       Xa, x_bf, (const float*)nullptr, Wf_in + (size_t)1 * 256 * 1024, b_in + 256,
                       G1, G1_f8, stats + 1 * 1024, N);
    hipLaunchKernelGGL((gemm_lds_kernel<512, 512, false>), ggrid2, blk, 0, stream,
                       Xa, x_bf, (const float*)nullptr, Wf_in + (size_t)2 * 256 * 1024, b_in + 512,
                       G2, G2_f8, stats + 2 * 1024, N);
    hipLaunchKernelGGL(bn_finalize3_kernel, dim3(3), dim3(256), 0, stream,
                       stats, g_in, be_in, N);

    float* kp0 = stats + 0 * 1024 + 512;
    float* kp1 = stats + 1 * 1024 + 512;
    float* kp2 = stats + 2 * 1024 + 512;
    float* st3 = stats + 3 * 1024;
    float* st4 = stats + 4 * 1024;
    float* st5 = stats + 5 * 1024;

    // ---- fused dual gather: Ha = A@bn(G1), Ha2 = A@bn(G2) ----
    hipLaunchKernelGGL(spmm256x2bn_kernel, sgrid, blk, 0, stream,
                       row_ptr, meta, G1_f8, kp1, G2_f8, kp2, Ha, Ha2, N);

    // ---- j = 1: gemm -> F1 ----
    hipLaunchKernelGGL((gemm_lds_kernel<256, 256, true>), ggrid2, blk, 0, stream,
                       Ha, G1, kp1, Wf_h, b_h, F1, (unsigned char*)nullptr, st3, N);
    hipLaunchKernelGGL(bn_finalize_kernel, dim3(1), dim3(256), 0, stream, st3, g_h, be_h, st3 + 512, N);

    // ---- j = 2: two hidden GCs ----
    hipLaunchKernelGGL((gemm_lds_kernel<256, 256, true>), ggrid2, blk, 0, stream,
                       Ha2, G2, kp2, Wf_h + (size_t)1 * 256 * 512, b_h + 256,
                       H2, H2_f8, st4, N);
    hipLaunchKernelGGL(bn_finalize_kernel, dim3(1), dim3(256), 0, stream, st4, g_h + 256, be_h + 256, st4 + 512, N);

    hipLaunchKernelGGL(spmm256bn_kernel, sgrid, blk, 0, stream, row_ptr, meta, H2_f8, st4 + 512, Ha, N);
    hipLaunchKernelGGL((gemm_lds_kernel<256, 256, true>), ggrid2, blk, 0, stream,
                       Ha, H2, st4 + 512, Wf_h + (size_t)2 * 256 * 512, b_h + 512,
                       F2, (unsigned char*)nullptr, st5, N);
    hipLaunchKernelGGL(bn_finalize_kernel, dim3(1), dim3(256), 0, stream, st5, g_h + 512, be_h + 512, st5 + 512, N);

    // ---- final outproj ----
    hipLaunchKernelGGL(outproj_mfma_kernel, ogrid, blk, 0, stream,
                       x_bf, F0, kp0, F1, st3 + 512, F2, st5 + 512,
                       Wcb, bc, out, N);
}

// Round 13
// 1767.572 us; speedup vs baseline: 1.4134x; 1.4134x over previous
//
#include <hip/hip_runtime.h>

typedef __attribute__((ext_vector_type(8))) short bf16x8;
typedef __attribute__((ext_vector_type(2))) float f32x2;
typedef __attribute__((ext_vector_type(4))) float f32x4;
typedef __attribute__((ext_vector_type(4))) unsigned short u16x4;
typedef __attribute__((ext_vector_type(8))) unsigned short u16x8;

__device__ __forceinline__ float bf2f(unsigned short u) {
    union { unsigned int i; float f; } v; v.i = ((unsigned int)u) << 16; return v.f;
}
__device__ __forceinline__ unsigned short f2bf(float f) {
    union { float f; unsigned int i; } v; v.f = f;
    unsigned int b = v.i;
    b += 0x7FFFu + ((b >> 16) & 1u);   // round-to-nearest-even
    return (unsigned short)(b >> 16);
}
__device__ __forceinline__ unsigned char f2f8(float f) {
    int p = __builtin_amdgcn_cvt_pk_fp8_f32(f, f, 0, false);
    return (unsigned char)(p & 0xFF);
}
// decode meta word: src = m >> 8, w = fp8(m & 0xFF) * 2^-5
__device__ __forceinline__ float meta_w(unsigned int m) {
    f32x2 lo = __builtin_amdgcn_cvt_pk_f32_fp8(m & 0xFFu, false);
    return lo[0] * 0.03125f;
}

// ---------------- fused weight transpose: W,SW [L][K][256] -> Wf[L][256][2*Kp] bf16 ----------------
__global__ __launch_bounds__(256) void transpose_fused_kernel(
    const float* __restrict__ W, const float* __restrict__ SW,
    unsigned short* __restrict__ Wf, int K, int Kp, int L)
{
    long long total = (long long)L * 256 * 2 * Kp;
    long long idx = (long long)blockIdx.x * blockDim.x + threadIdx.x;
    const long long stride = (long long)gridDim.x * blockDim.x;
    for (; idx < total; idx += stride) {
        int l = (int)(idx / ((long long)256 * 2 * Kp));
        long long rem = idx - (long long)l * 256 * 2 * Kp;
        int c = (int)(rem / (2 * Kp));
        int kk = (int)(rem - (long long)c * 2 * Kp);
        const float* src = (kk < Kp) ? W : SW;
        int k = (kk < Kp) ? kk : kk - Kp;
        float v = (k < K) ? src[((size_t)l * K + k) * 256 + c] : 0.f;
        Wf[idx] = f2bf(v);
    }
}

// ---------------- Wc[1268][40] fp32 -> Wcb[48][1280] bf16 ----------------
__global__ __launch_bounds__(256) void transpose_wc_kernel(
    const float* __restrict__ Wc, unsigned short* __restrict__ Wcb)
{
    int idx = blockIdx.x * blockDim.x + threadIdx.x;
    if (idx >= 48 * 1280) return;
    int c = idx / 1280;
    int kk = idx - c * 1280;
    int src = -1;
    if (kk < 512)       { if (kk < 500) src = kk; }
    else if (kk < 768)  src = 500 + (kk - 512);
    else if (kk < 1024) src = 756 + (kk - 768);
    else                src = 1012 + (kk - 1024);
    float v = (c < 40 && src >= 0) ? Wc[(size_t)src * 40 + c] : 0.f;
    Wcb[idx] = f2bf(v);
}

// ---------------- x -> bf16 [N][512] AND fp8 [N][512] ----------------
__global__ __launch_bounds__(256) void cvtx_kernel(
    const float* __restrict__ X, unsigned short* __restrict__ Xb,
    unsigned char* __restrict__ X8, int N)
{
    long long total = (long long)N * 64;
    long long idx = (long long)blockIdx.x * blockDim.x + threadIdx.x;
    const long long stride = (long long)gridDim.x * blockDim.x;
    for (; idx < total; idx += stride) {
        long long row = idx >> 6;
        int g = (int)(idx & 63);
        int k0 = g * 8;
        float v[8];
        if (k0 + 8 <= 500) {
            float4 q0 = *reinterpret_cast<const float4*>(X + row * 500 + k0);
            float4 q1 = *reinterpret_cast<const float4*>(X + row * 500 + k0 + 4);
            v[0] = q0.x; v[1] = q0.y; v[2] = q0.z; v[3] = q0.w;
            v[4] = q1.x; v[5] = q1.y; v[6] = q1.z; v[7] = q1.w;
        } else {
#pragma unroll
            for (int j = 0; j < 8; ++j) v[j] = (k0 + j < 500) ? X[row * 500 + k0 + j] : 0.f;
        }
        u16x8 o;
#pragma unroll
        for (int j = 0; j < 8; ++j) o[j] = f2bf(v[j]);
        *reinterpret_cast<u16x8*>(Xb + row * 512 + k0) = o;
        int p0 = 0, p1 = 0;
        p0 = __builtin_amdgcn_cvt_pk_fp8_f32(v[0], v[1], p0, false);
        p0 = __builtin_amdgcn_cvt_pk_fp8_f32(v[2], v[3], p0, true);
        p1 = __builtin_amdgcn_cvt_pk_fp8_f32(v[4], v[5], p1, false);
        p1 = __builtin_amdgcn_cvt_pk_fp8_f32(v[6], v[7], p1, true);
        uint2 pk = make_uint2((unsigned int)p0, (unsigned int)p1);
        *reinterpret_cast<uint2*>(X8 + row * 512 + k0) = pk;
    }
}

// ---------------- CSR build ----------------
// hist also records each edge's rank within its dst row (atomic return value).
__global__ __launch_bounds__(256) void hist_kernel(
    const int* __restrict__ edst, int* __restrict__ cnt,
    int* __restrict__ rank, int n_edges)
{
    int idx = blockIdx.x * blockDim.x + threadIdx.x;
    const int stride = gridDim.x * blockDim.x;
    for (; idx < n_edges; idx += stride)
        rank[idx] = atomicAdd(&cnt[edst[idx]], 1);
}

__global__ __launch_bounds__(256) void scan1_kernel(
    const int* __restrict__ cnt, int* __restrict__ excl,
    int* __restrict__ blocksums, int n)
{
    __shared__ int s[256];
    const int tid = threadIdx.x;
    const int i = blockIdx.x * 256 + tid;
    int v = (i < n) ? cnt[i] : 0;
    s[tid] = v;
    __syncthreads();
#pragma unroll
    for (int off = 1; off < 256; off <<= 1) {
        int t = s[tid];
        if (tid >= off) t += s[tid - off];
        __syncthreads();
        s[tid] = t;
        __syncthreads();
    }
    if (i < n) excl[i] = s[tid] - v;
    if (tid == 255) blocksums[blockIdx.x] = s[255];
}

__global__ __launch_bounds__(512) void scan2_kernel(int* __restrict__ blocksums, int nb)
{
    __shared__ int s[512];
    const int tid = threadIdx.x;
    int v = (tid < nb) ? blocksums[tid] : 0;
    s[tid] = v;
    __syncthreads();
#pragma unroll
    for (int off = 1; off < 512; off <<= 1) {
        int t = s[tid];
        if (tid >= off) t += s[tid - off];
        __syncthreads();
        s[tid] = t;
        __syncthreads();
    }
    if (tid < nb) blocksums[tid] = s[tid] - v;
}

__global__ __launch_bounds__(256) void scan3_kernel(
    const int* __restrict__ excl, const int* __restrict__ blocksums,
    int* __restrict__ row_ptr, int n, int n_edges)
{
    const int i = blockIdx.x * 256 + threadIdx.x;
    if (i < n)
        row_ptr[i] = excl[i] + blocksums[i >> 8];
    if (i == 0) row_ptr[n] = n_edges;
}

// ---------------- XCD-striped scatter: pos = row_ptr[dst] + rank, no atomics ----------------
// blockIdx&7 selects the dst-range stripe; blocks with the same (blockIdx&7) land on
// the same XCD (round-robin heuristic) so each meta stripe's write lines stay in ONE
// L2 and merge before eviction. Correct regardless of actual mapping.
__global__ __launch_bounds__(256) void scatter_kernel(
    const int* __restrict__ esrc, const int* __restrict__ edst,
    const float* __restrict__ ew, const int* __restrict__ rank,
    const int* __restrict__ row_ptr, unsigned int* __restrict__ meta,
    int n_edges, int nper)
{
    const int stripe = blockIdx.x & 7;
    const int lo = stripe * nper;
    const int hi = lo + nper;
    int idx = (blockIdx.x >> 3) * blockDim.x + threadIdx.x;
    const int stride = (gridDim.x >> 3) * blockDim.x;
    for (; idx < n_edges; idx += stride) {
        int d = edst[idx];
        if (d < lo || d >= hi) continue;
        int pos = row_ptr[d] + rank[idx];
        unsigned int m = ((unsigned int)esrc[idx] << 8) | f2f8(ew[idx] * 32.0f);
        meta[pos] = m;
    }
}

// ---------------- SpMM 256-wide, fp8 source, on-the-fly BN+ReLU ----------------
__global__ __launch_bounds__(256) void spmm256bn_kernel(
    const int* __restrict__ row_ptr, const unsigned int* __restrict__ meta,
    const unsigned char* __restrict__ S8, const float* __restrict__ kp,
    unsigned short* __restrict__ O, int N)
{
    const int wave = threadIdx.x >> 6;
    const int lane = threadIdx.x & 63;
    int node = blockIdx.x * 4 + wave;
    if (node >= N) return;
    node = __builtin_amdgcn_readfirstlane(node);
    const int beg = row_ptr[node];
    const int end = row_ptr[node + 1];
    const f32x4 sc = *reinterpret_cast<const f32x4*>(kp + lane * 4);
    const f32x4 sh = *reinterpret_cast<const f32x4*>(kp + 256 + lane * 4);
    float a0 = 0.f, a1 = 0.f, a2 = 0.f, a3 = 0.f;

    int e = beg;
    for (; e + 12 <= end; e += 12) {
        unsigned int m[12];
#pragma unroll
        for (int j = 0; j < 12; ++j) m[j] = meta[e + j];
        unsigned int v[12];
#pragma unroll
        for (int j = 0; j < 12; ++j)
            v[j] = *reinterpret_cast<const unsigned int*>(S8 + (size_t)(m[j] >> 8) * 256 + lane * 4);
#pragma unroll
        for (int j = 0; j < 12; ++j) {
            float w = meta_w(m[j]);
            f32x2 lo = __builtin_amdgcn_cvt_pk_f32_fp8(v[j], false);
            f32x2 hi = __builtin_amdgcn_cvt_pk_f32_fp8(v[j], true);
            a0 = fmaf(w, fmaxf(fmaf(lo[0], sc[0], sh[0]), 0.f), a0);
            a1 = fmaf(w, fmaxf(fmaf(lo[1], sc[1], sh[1]), 0.f), a1);
            a2 = fmaf(w, fmaxf(fmaf(hi[0], sc[2], sh[2]), 0.f), a2);
            a3 = fmaf(w, fmaxf(fmaf(hi[1], sc[3], sh[3]), 0.f), a3);
        }
    }
    for (; e < end; ++e) {
        unsigned int m = meta[e];
        float w = meta_w(m);
        unsigned int v = *reinterpret_cast<const unsigned int*>(S8 + (size_t)(m >> 8) * 256 + lane * 4);
        f32x2 lo = __builtin_amdgcn_cvt_pk_f32_fp8(v, false);
        f32x2 hi = __builtin_amdgcn_cvt_pk_f32_fp8(v, true);
        a0 = fmaf(w, fmaxf(fmaf(lo[0], sc[0], sh[0]), 0.f), a0);
        a1 = fmaf(w, fmaxf(fmaf(lo[1], sc[1], sh[1]), 0.f), a1);
        a2 = fmaf(w, fmaxf(fmaf(hi[0], sc[2], sh[2]), 0.f), a2);
        a3 = fmaf(w, fmaxf(fmaf(hi[1], sc[3], sh[3]), 0.f), a3);
    }
    u16x4 o;
    o[0] = f2bf(a0); o[1] = f2bf(a1); o[2] = f2bf(a2); o[3] = f2bf(a3);
    *reinterpret_cast<u16x4*>(O + (size_t)node * 256 + lane * 4) = o;
}

// ---------------- fused dual SpMM 256-wide ----------------
__global__ __launch_bounds__(256) void spmm256x2bn_kernel(
    const int* __restrict__ row_ptr, const unsigned int* __restrict__ meta,
    const unsigned char* __restrict__ S8a, const float* __restrict__ kpa,
    const unsigned char* __restrict__ S8b, const float* __restrict__ kpb,
    unsigned short* __restrict__ Oa, unsigned short* __restrict__ Ob, int N)
{
    const int wave = threadIdx.x >> 6;
    const int lane = threadIdx.x & 63;
    int node = blockIdx.x * 4 + wave;
    if (node >= N) return;
    node = __builtin_amdgcn_readfirstlane(node);
    const int beg = row_ptr[node];
    const int end = row_ptr[node + 1];
    const f32x4 sca = *reinterpret_cast<const f32x4*>(kpa + lane * 4);
    const f32x4 sha = *reinterpret_cast<const f32x4*>(kpa + 256 + lane * 4);
    const f32x4 scb = *reinterpret_cast<const f32x4*>(kpb + lane * 4);
    const f32x4 shb = *reinterpret_cast<const f32x4*>(kpb + 256 + lane * 4);
    float a0 = 0.f, a1 = 0.f, a2 = 0.f, a3 = 0.f;
    float b0 = 0.f, b1 = 0.f, b2 = 0.f, b3 = 0.f;

    int e = beg;
    for (; e + 8 <= end; e += 8) {
        unsigned int m[8];
#pragma unroll
        for (int j = 0; j < 8; ++j) m[j] = meta[e + j];
        unsigned int va[8], vb[8];
#pragma unroll
        for (int j = 0; j < 8; ++j) {
            size_t off = (size_t)(m[j] >> 8) * 256 + lane * 4;
            va[j] = *reinterpret_cast<const unsigned int*>(S8a + off);
            vb[j] = *reinterpret_cast<const unsigned int*>(S8b + off);
        }
#pragma unroll
        for (int j = 0; j < 8; ++j) {
            float w = meta_w(m[j]);
            f32x2 alo = __builtin_amdgcn_cvt_pk_f32_fp8(va[j], false);
            f32x2 ahi = __builtin_amdgcn_cvt_pk_f32_fp8(va[j], true);
            f32x2 blo = __builtin_amdgcn_cvt_pk_f32_fp8(vb[j], false);
            f32x2 bhi = __builtin_amdgcn_cvt_pk_f32_fp8(vb[j], true);
            a0 = fmaf(w, fmaxf(fmaf(alo[0], sca[0], sha[0]), 0.f), a0);
            a1 = fmaf(w, fmaxf(fmaf(alo[1], sca[1], sha[1]), 0.f), a1);
            a2 = fmaf(w, fmaxf(fmaf(ahi[0], sca[2], sha[2]), 0.f), a2);
            a3 = fmaf(w, fmaxf(fmaf(ahi[1], sca[3], sha[3]), 0.f), a3);
            b0 = fmaf(w, fmaxf(fmaf(blo[0], scb[0], shb[0]), 0.f), b0);
            b1 = fmaf(w, fmaxf(fmaf(blo[1], scb[1], shb[1]), 0.f), b1);
            b2 = fmaf(w, fmaxf(fmaf(bhi[0], scb[2], shb[2]), 0.f), b2);
            b3 = fmaf(w, fmaxf(fmaf(bhi[1], scb[3], shb[3]), 0.f), b3);
        }
    }
    for (; e < end; ++e) {
        unsigned int m = meta[e];
        float w = meta_w(m);
        size_t off = (size_t)(m >> 8) * 256 + lane * 4;
        unsigned int va = *reinterpret_cast<const unsigned int*>(S8a + off);
        unsigned int vb = *reinterpret_cast<const unsigned int*>(S8b + off);
        f32x2 alo = __builtin_amdgcn_cvt_pk_f32_fp8(va, false);
        f32x2 ahi = __builtin_amdgcn_cvt_pk_f32_fp8(va, true);
        f32x2 blo = __builtin_amdgcn_cvt_pk_f32_fp8(vb, false);
        f32x2 bhi = __builtin_amdgcn_cvt_pk_f32_fp8(vb, true);
        a0 = fmaf(w, fmaxf(fmaf(alo[0], sca[0], sha[0]), 0.f), a0);
        a1 = fmaf(w, fmaxf(fmaf(alo[1], sca[1], sha[1]), 0.f), a1);
        a2 = fmaf(w, fmaxf(fmaf(ahi[0], sca[2], sha[2]), 0.f), a2);
        a3 = fmaf(w, fmaxf(fmaf(ahi[1], sca[3], sha[3]), 0.f), a3);
        b0 = fmaf(w, fmaxf(fmaf(blo[0], scb[0], shb[0]), 0.f), b0);
        b1 = fmaf(w, fmaxf(fmaf(blo[1], scb[1], shb[1]), 0.f), b1);
        b2 = fmaf(w, fmaxf(fmaf(bhi[0], scb[2], shb[2]), 0.f), b2);
        b3 = fmaf(w, fmaxf(fmaf(bhi[1], scb[3], shb[3]), 0.f), b3);
    }
    u16x4 oa, ob;
    oa[0] = f2bf(a0); oa[1] = f2bf(a1); oa[2] = f2bf(a2); oa[3] = f2bf(a3);
    ob[0] = f2bf(b0); ob[1] = f2bf(b1); ob[2] = f2bf(b2); ob[3] = f2bf(b3);
    *reinterpret_cast<u16x4*>(Oa + (size_t)node * 256 + lane * 4) = oa;
    *reinterpret_cast<u16x4*>(Ob + (size_t)node * 256 + lane * 4) = ob;
}

// ---------------- SpMM 512-wide, fp8 source: TWO waves per node, 8-deep ----------------
__global__ __launch_bounds__(512) void spmm512_kernel(
    const int* __restrict__ row_ptr, const unsigned int* __restrict__ meta,
    const unsigned char* __restrict__ S8, unsigned short* __restrict__ O, int N)
{
    const int wv = threadIdx.x >> 6;
    const int lane = threadIdx.x & 63;
    const int half = wv & 1;
    int node = blockIdx.x * 4 + (wv >> 1);
    if (node >= N) return;
    node = __builtin_amdgcn_readfirstlane(node);
    const int beg = row_ptr[node];
    const int end = row_ptr[node + 1];
    const int coff = half * 256 + lane * 4;
    float a0 = 0.f, a1 = 0.f, a2 = 0.f, a3 = 0.f;

    int e = beg;
    for (; e + 8 <= end; e += 8) {
        unsigned int m[8];
#pragma unroll
        for (int j = 0; j < 8; ++j) m[j] = meta[e + j];
        unsigned int v[8];
#pragma unroll
        for (int j = 0; j < 8; ++j)
            v[j] = *reinterpret_cast<const unsigned int*>(S8 + (size_t)(m[j] >> 8) * 512 + coff);
#pragma unroll
        for (int j = 0; j < 8; ++j) {
            float w = meta_w(m[j]);
            f32x2 lo = __builtin_amdgcn_cvt_pk_f32_fp8(v[j], false);
            f32x2 hi = __builtin_amdgcn_cvt_pk_f32_fp8(v[j], true);
            a0 = fmaf(w, lo[0], a0);
            a1 = fmaf(w, lo[1], a1);
            a2 = fmaf(w, hi[0], a2);
            a3 = fmaf(w, hi[1], a3);
        }
    }
    for (; e < end; ++e) {
        unsigned int m = meta[e];
        float w = meta_w(m);
        unsigned int v = *reinterpret_cast<const unsigned int*>(S8 + (size_t)(m >> 8) * 512 + coff);
        f32x2 lo = __builtin_amdgcn_cvt_pk_f32_fp8(v, false);
        f32x2 hi = __builtin_amdgcn_cvt_pk_f32_fp8(v, true);
        a0 = fmaf(w, lo[0], a0);
        a1 = fmaf(w, lo[1], a1);
        a2 = fmaf(w, hi[0], a2);
        a3 = fmaf(w, hi[1], a3);
    }
    u16x4 o;
    o[0] = f2bf(a0); o[1] = f2bf(a1); o[2] = f2bf(a2); o[3] = f2bf(a3);
    *reinterpret_cast<u16x4*>(O + (size_t)node * 512 + coff) = o;
}

// ---------------- LDS-staged MFMA GEMM ----------------
template<int K1, int K2, bool BN2>
__global__ __launch_bounds__(256) void gemm_lds_kernel(
    const unsigned short* __restrict__ A1, const unsigned short* __restrict__ A2,
    const float* __restrict__ kp, const unsigned short* __restrict__ Btf,
    const float* __restrict__ bias, unsigned short* __restrict__ Cout,
    unsigned char* __restrict__ C8, float* __restrict__ stats, int N)
{
    constexpr int KT = K1 + K2;
    __shared__ unsigned short Atile[128 * 64];
    __shared__ unsigned short Btile[128 * 64];

    const int lane = threadIdx.x & 63;
    const int wave = threadIdx.x >> 6;
    const int l16 = lane & 15;
    const int khi = lane >> 4;
    const int wm = wave >> 1;
    const int wn = wave & 1;
    const long long bm = (long long)blockIdx.x * 128;
    const int col0 = blockIdx.y * 128;

    const int srow8 = lane >> 3;
    const int sc16 = lane & 7;

    f32x4 acc[4][4];
#pragma unroll
    for (int m = 0; m < 4; ++m)
#pragma unroll
        for (int n = 0; n < 4; ++n) acc[m][n] = (f32x4){0.f, 0.f, 0.f, 0.f};

    for (int k0 = 0; k0 < KT; k0 += 64) {
        const unsigned short* Aseg;
        int koff, astr;
        if (k0 < K1) { Aseg = A1; koff = k0; astr = K1; }
        else         { Aseg = A2; koff = k0 - K1; astr = K2; }
        const bool bnseg = BN2 && (k0 >= K1);

        u16x8 av[4], bv[4];
        int rloc[4];
#pragma unroll
        for (int i = 0; i < 4; ++i) {
            int r = wave * 32 + i * 8 + srow8;
            rloc[i] = r;
            long long gr = bm + r;
            if (gr >= N) gr = N - 1;
            av[i] = *reinterpret_cast<const u16x8*>(Aseg + (size_t)gr * astr + koff + sc16 * 8);
            bv[i] = *reinterpret_cast<const u16x8*>(Btf + (size_t)(col0 + r) * KT + k0 + sc16 * 8);
        }
        __syncthreads();
#pragma unroll
        for (int i = 0; i < 4; ++i) {
            int r = rloc[i];
            int cw = (sc16 ^ (r & 7)) * 8;
            *reinterpret_cast<u16x8*>(&Atile[r * 64 + cw]) = av[i];
            *reinterpret_cast<u16x8*>(&Btile[r * 64 + cw]) = bv[i];
        }
        __syncthreads();

#pragma unroll
        for (int kk = 0; kk < 2; ++kk) {
            const int kc = kk * 4 + khi;
            bf16x8 a[4], b[4];
#pragma unroll
            for (int m = 0; m < 4; ++m) {
                int ra = wm * 64 + m * 16 + l16;
                a[m] = *reinterpret_cast<const bf16x8*>(&Atile[ra * 64 + ((kc ^ (ra & 7)) * 8)]);
            }
            if (bnseg) {
                int ch = (k0 - K1) + kk * 32 + khi * 8;
                f32x4 s0 = *reinterpret_cast<const f32x4*>(kp + ch);
                f32x4 s1 = *reinterpret_cast<const f32x4*>(kp + ch + 4);
                f32x4 t0 = *reinterpret_cast<const f32x4*>(kp + 256 + ch);
                f32x4 t1 = *reinterpret_cast<const f32x4*>(kp + 256 + ch + 4);
#pragma unroll
                for (int m = 0; m < 4; ++m) {
                    u16x8 raw;
                    __builtin_memcpy(&raw, &a[m], 16);
                    u16x8 ov;
#pragma unroll
                    for (int j = 0; j < 4; ++j) {
                        ov[j]     = f2bf(fmaxf(fmaf(bf2f(raw[j]),     s0[j], t0[j]), 0.f));
                        ov[4 + j] = f2bf(fmaxf(fmaf(bf2f(raw[4 + j]), s1[j], t1[j]), 0.f));
                    }
                    __builtin_memcpy(&a[m], &ov, 16);
                }
            }
#pragma unroll
            for (int n = 0; n < 4; ++n) {
                int rb = wn * 64 + n * 16 + l16;
                b[n] = *reinterpret_cast<const bf16x8*>(&Btile[rb * 64 + ((kc ^ (rb & 7)) * 8)]);
            }
#pragma unroll
            for (int m = 0; m < 4; ++m)
#pragma unroll
                for (int n = 0; n < 4; ++n)
                    acc[m][n] = __builtin_amdgcn_mfma_f32_16x16x32_bf16(a[m], b[n], acc[m][n], 0, 0, 0);
        }
    }

    float bs[4];
#pragma unroll
    for (int n = 0; n < 4; ++n) bs[n] = bias[col0 + wn * 64 + n * 16 + l16];

    float s[4], s2[4];
#pragma unroll
    for (int n = 0; n < 4; ++n) { s[n] = 0.f; s2[n] = 0.f; }

#pragma unroll
    for (int m = 0; m < 4; ++m)
#pragma unroll
        for (int r = 0; r < 4; ++r) {
            long long grow = bm + wm * 64 + m * 16 + khi * 4 + r;
            if (grow >= N) continue;
#pragma unroll
            for (int n = 0; n < 4; ++n) {
                int gcol = col0 + wn * 64 + n * 16 + l16;
                float v = acc[m][n][r] + bs[n];
                Cout[grow * 256 + gcol] = f2bf(v);
                if (C8) C8[grow * 256 + gcol] = f2f8(v);
                s[n] += v;
                s2[n] = fmaf(v, v, s2[n]);
            }
        }

#pragma unroll
    for (int n = 0; n < 4; ++n) {
        float a = s[n], b2 = s2[n];
        a += __shfl_xor(a, 16); a += __shfl_xor(a, 32);
        b2 += __shfl_xor(b2, 16); b2 += __shfl_xor(b2, 32);
        if (khi == 0) {
            int c = col0 + wn * 64 + n * 16 + l16;
            atomicAdd(&stats[c], a);
            atomicAdd(&stats[256 + c], b2);
        }
    }
}

// ---------------- BN finalize ----------------
__global__ __launch_bounds__(256) void bn_finalize_kernel(
    const float* __restrict__ sums, const float* __restrict__ g,
    const float* __restrict__ be, float* __restrict__ kp, int N)
{
    const int c = threadIdx.x;
    float invN = 1.f / (float)N;
    float mean = sums[c] * invN;
    float var = sums[256 + c] * invN - mean * mean;
    float inv = rsqrtf(var + 1e-5f);
    float sc = g[c] * inv;
    kp[c] = sc;
    kp[256 + c] = be[c] - sc * mean;
}

__global__ __launch_bounds__(256) void bn_finalize3_kernel(
    float* __restrict__ stats, const float* __restrict__ g,
    const float* __restrict__ be, int N)
{
    const int l = blockIdx.x;
    const int c = threadIdx.x;
    float* st = stats + (size_t)l * 1024;
    float invN = 1.f / (float)N;
    float mean = st[c] * invN;
    float var = st[256 + c] * invN - mean * mean;
    float inv = rsqrtf(var + 1e-5f);
    float sc = g[l * 256 + c] * inv;
    st[512 + c] = sc;
    st[768 + c] = be[l * 256 + c] - sc * mean;
}

// ---------------- final MFMA outproj ----------------
template<int KS, bool BN>
__device__ __forceinline__ void outproj_seg(
    const unsigned short* __restrict__ seg, const float* __restrict__ kp,
    const unsigned short* __restrict__ Wcb, int bOff,
    long long r0, long long r1, int l16, int khi, f32x4 acc[2][3])
{
    const unsigned short* a0p = seg + (size_t)r0 * KS + khi * 8;
    const unsigned short* a1p = seg + (size_t)r1 * KS + khi * 8;
#pragma unroll
    for (int k0 = 0; k0 < KS; k0 += 32) {
        bf16x8 a[2];
        a[0] = *reinterpret_cast<const bf16x8*>(a0p + k0);
        a[1] = *reinterpret_cast<const bf16x8*>(a1p + k0);
        if (BN) {
            int ch0 = k0 + khi * 8;
            f32x4 s0 = *reinterpret_cast<const f32x4*>(kp + ch0);
            f32x4 s1 = *reinterpret_cast<const f32x4*>(kp + ch0 + 4);
            f32x4 t0 = *reinterpret_cast<const f32x4*>(kp + 256 + ch0);
            f32x4 t1 = *reinterpret_cast<const f32x4*>(kp + 256 + ch0 + 4);
#pragma unroll
            for (int m = 0; m < 2; ++m) {
                u16x8 raw;
                __builtin_memcpy(&raw, &a[m], 16);
                u16x8 ov;
#pragma unroll
                for (int j = 0; j < 4; ++j) {
                    ov[j]     = f2bf(fmaxf(fmaf(bf2f(raw[j]),     s0[j], t0[j]), 0.f));
                    ov[4 + j] = f2bf(fmaxf(fmaf(bf2f(raw[4 + j]), s1[j], t1[j]), 0.f));
                }
                __builtin_memcpy(&a[m], &ov, 16);
            }
        }
        bf16x8 b[3];
#pragma unroll
        for (int nt = 0; nt < 3; ++nt)
            b[nt] = *reinterpret_cast<const bf16x8*>(Wcb + (size_t)(nt * 16 + l16) * 1280 + bOff + k0 + khi * 8);
#pragma unroll
        for (int m = 0; m < 2; ++m)
#pragma unroll
            for (int nt = 0; nt < 3; ++nt)
                acc[m][nt] = __builtin_amdgcn_mfma_f32_16x16x32_bf16(a[m], b[nt], acc[m][nt], 0, 0, 0);
    }
}

__global__ __launch_bounds__(256) void outproj_mfma_kernel(
    const unsigned short* __restrict__ x_bf,
    const unsigned short* __restrict__ F0, const float* __restrict__ kp0,
    const unsigned short* __restrict__ F1, const float* __restrict__ kp1,
    const unsigned short* __restrict__ F2, const float* __restrict__ kp2,
    const unsigned short* __restrict__ Wcb, const float* __restrict__ bc,
    float* __restrict__ out, int N)
{
    const int lane = threadIdx.x & 63;
    const int wave = threadIdx.x >> 6;
    const int l16 = lane & 15;
    const int khi = lane >> 4;
    const long long bm = (long long)blockIdx.x * 128 + wave * 32;

    long long r0 = bm + l16;        if (r0 >= N) r0 = 0;
    long long r1 = bm + 16 + l16;   if (r1 >= N) r1 = 0;

    f32x4 acc[2][3];
#pragma unroll
    for (int m = 0; m < 2; ++m)
#pragma unroll
        for (int nt = 0; nt < 3; ++nt) acc[m][nt] = (f32x4){0.f, 0.f, 0.f, 0.f};

    outproj_seg<512, false>(x_bf, nullptr, Wcb, 0,    r0, r1, l16, khi, acc);
    outproj_seg<256, true >(F0,   kp0,     Wcb, 512,  r0, r1, l16, khi, acc);
    outproj_seg<256, true >(F1,   kp1,     Wcb, 768,  r0, r1, l16, khi, acc);
    outproj_seg<256, true >(F2,   kp2,     Wcb, 1024, r0, r1, l16, khi, acc);

#pragma unroll
    for (int m = 0; m < 2; ++m)
#pragma unroll
        for (int nt = 0; nt < 3; ++nt)
#pragma unroll
            for (int r = 0; r < 4; ++r) {
                long long grow = bm + m * 16 + khi * 4 + r;
                int gcol = nt * 16 + l16;
                if (grow < N && gcol < 40)
                    out[grow * 40 + gcol] = acc[m][nt][r] + bc[gcol];
            }
}

// ---------------- host-side orchestration ----------------
extern "C" void kernel_launch(void* const* d_in, const int* in_sizes, int n_in,
                              void* d_out, int out_size, void* d_ws, size_t ws_size,
                              hipStream_t stream)
{
    const float* x      = (const float*)d_in[0];
    const int*   esrc   = (const int*)d_in[1];
    const int*   edst   = (const int*)d_in[2];
    const float* ew     = (const float*)d_in[3];
    const float* W_in   = (const float*)d_in[4];
    const float* SW_in  = (const float*)d_in[5];
    const float* b_in   = (const float*)d_in[6];
    const float* g_in   = (const float*)d_in[7];
    const float* be_in  = (const float*)d_in[8];
    const float* W_h    = (const float*)d_in[9];
    const float* SW_h   = (const float*)d_in[10];
    const float* b_h    = (const float*)d_in[11];
    const float* g_h    = (const float*)d_in[12];
    const float* be_h   = (const float*)d_in[13];
    const float* Wc     = (const float*)d_in[14];
    const float* bc     = (const float*)d_in[15];
    float* out = (float*)d_out;

    const int N = in_sizes[0] / 500;      // 100000
    const int n_edges = in_sizes[1];      // 3200000
    const int nb = (N + 255) / 256;
    const int nper = (N + 7) / 8;         // dst-range per XCD stripe

    // ---- workspace layout ----
    char* p = (char*)d_ws;
    unsigned short* x_bf = (unsigned short*)p; p += (size_t)N * 512 * 2;
    unsigned short* Xa   = (unsigned short*)p; p += (size_t)N * 512 * 2;   // F2 aliases
    unsigned short* Ha   = (unsigned short*)p; p += (size_t)N * 256 * 2;
    unsigned short* Ha2  = (unsigned short*)p; p += (size_t)N * 256 * 2;
    unsigned short* G1   = (unsigned short*)p; p += (size_t)N * 256 * 2;   // H2 aliases
    unsigned short* G2   = (unsigned short*)p; p += (size_t)N * 256 * 2;
    unsigned short* F0   = (unsigned short*)p; p += (size_t)N * 256 * 2;
    unsigned short* F1   = (unsigned short*)p; p += (size_t)N * 256 * 2;
    unsigned short* H2   = G1;
    unsigned short* F2   = Xa;
    unsigned char* x_f8  = (unsigned char*)p; p += (size_t)N * 512;
    unsigned char* G1_f8 = (unsigned char*)p; p += (size_t)N * 256;
    unsigned char* G2_f8 = (unsigned char*)p; p += (size_t)N * 256;
    unsigned char* H2_f8 = G1_f8;   // alias: G1_f8 dead after dual spmm
    unsigned short* Wf_in = (unsigned short*)p; p += (size_t)3 * 256 * 1024 * 2;
    unsigned short* Wf_h  = (unsigned short*)p; p += (size_t)3 * 256 * 512 * 2;
    unsigned short* Wcb   = (unsigned short*)p; p += (size_t)48 * 1280 * 2;
    float* stats = (float*)p; p += (size_t)6 * 1024 * 4;
    int* cnt     = (int*)p; p += (size_t)N * 4;
    int* excl    = (int*)p; p += (size_t)N * 4;
    int* blocksums = (int*)p; p += 2048 * 4;
    int* row_ptr = (int*)p; p += (size_t)(N + 1) * 4 + 4;
    int* rank    = (int*)p; p += (size_t)n_edges * 4;
    unsigned int* meta = (unsigned int*)p;

    // ---- preprocessing ----
    hipMemsetAsync(stats, 0, (size_t)6 * 1024 * sizeof(float) + (size_t)N * sizeof(int), stream);
    hipLaunchKernelGGL(transpose_fused_kernel, dim3(2048), dim3(256), 0, stream,
                       W_in, SW_in, Wf_in, 500, 512, 3);
    hipLaunchKernelGGL(transpose_fused_kernel, dim3(1024), dim3(256), 0, stream,
                       W_h, SW_h, Wf_h, 256, 256, 3);
    hipLaunchKernelGGL(transpose_wc_kernel, dim3(240), dim3(256), 0, stream, Wc, Wcb);

    hipLaunchKernelGGL(hist_kernel, dim3(4096), dim3(256), 0, stream, edst, cnt, rank, n_edges);
    hipLaunchKernelGGL(scan1_kernel, dim3(nb), dim3(256), 0, stream, cnt, excl, blocksums, N);
    hipLaunchKernelGGL(scan2_kernel, dim3(1), dim3(512), 0, stream, blocksums, nb);
    hipLaunchKernelGGL(scan3_kernel, dim3(nb), dim3(256), 0, stream,
                       excl, blocksums, row_ptr, N, n_edges);
    hipLaunchKernelGGL(scatter_kernel, dim3(4096), dim3(256), 0, stream,
                       esrc, edst, ew, rank, row_ptr, meta, n_edges, nper);

    hipLaunchKernelGGL(cvtx_kernel, dim3(4096), dim3(256), 0, stream, x, x_bf, x_f8, N);

    hipLaunchKernelGGL(spmm512_kernel, dim3((N + 3) / 4), dim3(512), 0, stream,
                       row_ptr, meta, x_f8, Xa, N);

    dim3 blk(256);
    dim3 ggrid2((N + 127) / 128, 2);
    dim3 ogrid((N + 127) / 128);
    dim3 sgrid((N + 3) / 4);

    // ---- three input-layer GEMMs ----
    hipLaunchKernelGGL((gemm_lds_kernel<512, 512, false>), ggrid2, blk, 0, stream,
                       Xa, x_bf, (const float*)nullptr, Wf_in, b_in,
                       F0, (unsigned char*)nullptr, stats + 0 * 1024, N);
    hipLaunchKernelGGL((gemm_lds_kernel<512, 512, false>), ggrid2, blk, 0, stream,
                       Xa, x_bf, (const float*)nullptr, Wf_in + (size_t)1 * 256 * 1024, b_in + 256,
                       G1, G1_f8, stats + 1 * 1024, N);
    hipLaunchKernelGGL((gemm_lds_kernel<512, 512, false>), ggrid2, blk, 0, stream,
                       Xa, x_bf, (const float*)nullptr, Wf_in + (size_t)2 * 256 * 1024, b_in + 512,
                       G2, G2_f8, stats + 2 * 1024, N);
    hipLaunchKernelGGL(bn_finalize3_kernel, dim3(3), dim3(256), 0, stream,
                       stats, g_in, be_in, N);

    float* kp0 = stats + 0 * 1024 + 512;
    float* kp1 = stats + 1 * 1024 + 512;
    float* kp2 = stats + 2 * 1024 + 512;
    float* st3 = stats + 3 * 1024;
    float* st4 = stats + 4 * 1024;
    float* st5 = stats + 5 * 1024;

    // ---- fused dual gather: Ha = A@bn(G1), Ha2 = A@bn(G2) ----
    hipLaunchKernelGGL(spmm256x2bn_kernel, sgrid, blk, 0, stream,
                       row_ptr, meta, G1_f8, kp1, G2_f8, kp2, Ha, Ha2, N);

    // ---- j = 1: gemm -> F1 ----
    hipLaunchKernelGGL((gemm_lds_kernel<256, 256, true>), ggrid2, blk, 0, stream,
                       Ha, G1, kp1, Wf_h, b_h, F1, (unsigned char*)nullptr, st3, N);
    hipLaunchKernelGGL(bn_finalize_kernel, dim3(1), dim3(256), 0, stream, st3, g_h, be_h, st3 + 512, N);

    // ---- j = 2: two hidden GCs ----
    hipLaunchKernelGGL((gemm_lds_kernel<256, 256, true>), ggrid2, blk, 0, stream,
                       Ha2, G2, kp2, Wf_h + (size_t)1 * 256 * 512, b_h + 256,
                       H2, H2_f8, st4, N);
    hipLaunchKernelGGL(bn_finalize_kernel, dim3(1), dim3(256), 0, stream, st4, g_h + 256, be_h + 256, st4 + 512, N);

    hipLaunchKernelGGL(spmm256bn_kernel, sgrid, blk, 0, stream, row_ptr, meta, H2_f8, st4 + 512, Ha, N);
    hipLaunchKernelGGL((gemm_lds_kernel<256, 256, true>), ggrid2, blk, 0, stream,
                       Ha, H2, st4 + 512, Wf_h + (size_t)2 * 256 * 512, b_h + 512,
                       F2, (unsigned char*)nullptr, st5, N);
    hipLaunchKernelGGL(bn_finalize_kernel, dim3(1), dim3(256), 0, stream, st5, g_h + 512, be_h + 512, st5 + 512, N);

    // ---- final outproj ----
    hipLaunchKernelGGL(outproj_mfma_kernel, ogrid, blk, 0, stream,
                       x_bf, F0, kp0, F1, st3 + 512, F2, st5 + 512,
                       Wcb, bc, out, N);
}

// Round 14
// 1767.140 us; speedup vs baseline: 1.4138x; 1.0002x over previous
//
#include <hip/hip_runtime.h>

typedef __attribute__((ext_vector_type(8))) short bf16x8;
typedef __attribute__((ext_vector_type(2))) float f32x2;
typedef __attribute__((ext_vector_type(4))) float f32x4;
typedef __attribute__((ext_vector_type(4))) unsigned short u16x4;
typedef __attribute__((ext_vector_type(8))) unsigned short u16x8;

__device__ __forceinline__ float bf2f(unsigned short u) {
    union { unsigned int i; float f; } v; v.i = ((unsigned int)u) << 16; return v.f;
}
__device__ __forceinline__ unsigned short f2bf(float f) {
    union { float f; unsigned int i; } v; v.f = f;
    unsigned int b = v.i;
    b += 0x7FFFu + ((b >> 16) & 1u);   // round-to-nearest-even
    return (unsigned short)(b >> 16);
}
__device__ __forceinline__ unsigned char f2f8(float f) {
    int p = __builtin_amdgcn_cvt_pk_fp8_f32(f, f, 0, false);
    return (unsigned char)(p & 0xFF);
}
// decode meta word: src = m >> 8, w = fp8(m & 0xFF) * 2^-5
__device__ __forceinline__ float meta_w(unsigned int m) {
    f32x2 lo = __builtin_amdgcn_cvt_pk_f32_fp8(m & 0xFFu, false);
    return lo[0] * 0.03125f;
}

// ---------------- fused weight transpose: W,SW [L][K][256] -> Wf[L][256][2*Kp] bf16 ----------------
__global__ __launch_bounds__(256) void transpose_fused_kernel(
    const float* __restrict__ W, const float* __restrict__ SW,
    unsigned short* __restrict__ Wf, int K, int Kp, int L)
{
    long long total = (long long)L * 256 * 2 * Kp;
    long long idx = (long long)blockIdx.x * blockDim.x + threadIdx.x;
    const long long stride = (long long)gridDim.x * blockDim.x;
    for (; idx < total; idx += stride) {
        int l = (int)(idx / ((long long)256 * 2 * Kp));
        long long rem = idx - (long long)l * 256 * 2 * Kp;
        int c = (int)(rem / (2 * Kp));
        int kk = (int)(rem - (long long)c * 2 * Kp);
        const float* src = (kk < Kp) ? W : SW;
        int k = (kk < Kp) ? kk : kk - Kp;
        float v = (k < K) ? src[((size_t)l * K + k) * 256 + c] : 0.f;
        Wf[idx] = f2bf(v);
    }
}

// ---------------- Wc[1268][40] fp32 -> Wcb[48][1280] bf16 ----------------
__global__ __launch_bounds__(256) void transpose_wc_kernel(
    const float* __restrict__ Wc, unsigned short* __restrict__ Wcb)
{
    int idx = blockIdx.x * blockDim.x + threadIdx.x;
    if (idx >= 48 * 1280) return;
    int c = idx / 1280;
    int kk = idx - c * 1280;
    int src = -1;
    if (kk < 512)       { if (kk < 500) src = kk; }
    else if (kk < 768)  src = 500 + (kk - 512);
    else if (kk < 1024) src = 756 + (kk - 768);
    else                src = 1012 + (kk - 1024);
    float v = (c < 40 && src >= 0) ? Wc[(size_t)src * 40 + c] : 0.f;
    Wcb[idx] = f2bf(v);
}

// ---------------- x -> bf16 [N][512] AND fp8 [N][512] ----------------
__global__ __launch_bounds__(256) void cvtx_kernel(
    const float* __restrict__ X, unsigned short* __restrict__ Xb,
    unsigned char* __restrict__ X8, int N)
{
    long long total = (long long)N * 64;
    long long idx = (long long)blockIdx.x * blockDim.x + threadIdx.x;
    const long long stride = (long long)gridDim.x * blockDim.x;
    for (; idx < total; idx += stride) {
        long long row = idx >> 6;
        int g = (int)(idx & 63);
        int k0 = g * 8;
        float v[8];
        if (k0 + 8 <= 500) {
            float4 q0 = *reinterpret_cast<const float4*>(X + row * 500 + k0);
            float4 q1 = *reinterpret_cast<const float4*>(X + row * 500 + k0 + 4);
            v[0] = q0.x; v[1] = q0.y; v[2] = q0.z; v[3] = q0.w;
            v[4] = q1.x; v[5] = q1.y; v[6] = q1.z; v[7] = q1.w;
        } else {
#pragma unroll
            for (int j = 0; j < 8; ++j) v[j] = (k0 + j < 500) ? X[row * 500 + k0 + j] : 0.f;
        }
        u16x8 o;
#pragma unroll
        for (int j = 0; j < 8; ++j) o[j] = f2bf(v[j]);
        *reinterpret_cast<u16x8*>(Xb + row * 512 + k0) = o;
        int p0 = 0, p1 = 0;
        p0 = __builtin_amdgcn_cvt_pk_fp8_f32(v[0], v[1], p0, false);
        p0 = __builtin_amdgcn_cvt_pk_fp8_f32(v[2], v[3], p0, true);
        p1 = __builtin_amdgcn_cvt_pk_fp8_f32(v[4], v[5], p1, false);
        p1 = __builtin_amdgcn_cvt_pk_fp8_f32(v[6], v[7], p1, true);
        uint2 pk = make_uint2((unsigned int)p0, (unsigned int)p1);
        *reinterpret_cast<uint2*>(X8 + row * 512 + k0) = pk;
    }
}

// ---------------- CSR build ----------------
__global__ __launch_bounds__(256) void hist_kernel(
    const int* __restrict__ edst, int* __restrict__ cnt,
    int* __restrict__ rank, int n_edges)
{
    int idx = blockIdx.x * blockDim.x + threadIdx.x;
    const int stride = gridDim.x * blockDim.x;
    for (; idx < n_edges; idx += stride)
        rank[idx] = atomicAdd(&cnt[edst[idx]], 1);
}

__global__ __launch_bounds__(256) void scan1_kernel(
    const int* __restrict__ cnt, int* __restrict__ excl,
    int* __restrict__ blocksums, int n)
{
    __shared__ int s[256];
    const int tid = threadIdx.x;
    const int i = blockIdx.x * 256 + tid;
    int v = (i < n) ? cnt[i] : 0;
    s[tid] = v;
    __syncthreads();
#pragma unroll
    for (int off = 1; off < 256; off <<= 1) {
        int t = s[tid];
        if (tid >= off) t += s[tid - off];
        __syncthreads();
        s[tid] = t;
        __syncthreads();
    }
    if (i < n) excl[i] = s[tid] - v;
    if (tid == 255) blocksums[blockIdx.x] = s[255];
}

__global__ __launch_bounds__(512) void scan2_kernel(int* __restrict__ blocksums, int nb)
{
    __shared__ int s[512];
    const int tid = threadIdx.x;
    int v = (tid < nb) ? blocksums[tid] : 0;
    s[tid] = v;
    __syncthreads();
#pragma unroll
    for (int off = 1; off < 512; off <<= 1) {
        int t = s[tid];
        if (tid >= off) t += s[tid - off];
        __syncthreads();
        s[tid] = t;
        __syncthreads();
    }
    if (tid < nb) blocksums[tid] = s[tid] - v;
}

__global__ __launch_bounds__(256) void scan3_kernel(
    const int* __restrict__ excl, const int* __restrict__ blocksums,
    int* __restrict__ row_ptr, int n, int n_edges)
{
    const int i = blockIdx.x * 256 + threadIdx.x;
    if (i < n)
        row_ptr[i] = excl[i] + blocksums[i >> 8];
    if (i == 0) row_ptr[n] = n_edges;
}

// ---------------- XCD-striped scatter: pos = row_ptr[dst] + rank, no atomics ----------------
__global__ __launch_bounds__(256) void scatter_kernel(
    const int* __restrict__ esrc, const int* __restrict__ edst,
    const float* __restrict__ ew, const int* __restrict__ rank,
    const int* __restrict__ row_ptr, unsigned int* __restrict__ meta,
    int n_edges, int nper)
{
    const int stripe = blockIdx.x & 7;
    const int lo = stripe * nper;
    const int hi = lo + nper;
    int idx = (blockIdx.x >> 3) * blockDim.x + threadIdx.x;
    const int stride = (gridDim.x >> 3) * blockDim.x;
    for (; idx < n_edges; idx += stride) {
        int d = edst[idx];
        if (d < lo || d >= hi) continue;
        int pos = row_ptr[d] + rank[idx];
        unsigned int m = ((unsigned int)esrc[idx] << 8) | f2f8(ew[idx] * 32.0f);
        meta[pos] = m;
    }
}

// ---------------- bn+relu -> fp8 converters (run after bn_finalize) ----------------
// dual: GG8[node][g*8 .. g*8+3] = f8(relu(bn1(G1[ch 4g..4g+3]))), [g*8+4..] = same for G2
__global__ __launch_bounds__(256) void bnrelu2_f8_kernel(
    const unsigned short* __restrict__ G1, const float* __restrict__ kp1,
    const unsigned short* __restrict__ G2, const float* __restrict__ kp2,
    unsigned char* __restrict__ GG8, int N)
{
    long long total = (long long)N * 64;
    long long idx = (long long)blockIdx.x * blockDim.x + threadIdx.x;
    const long long stride = (long long)gridDim.x * blockDim.x;
    for (; idx < total; idx += stride) {
        long long node = idx >> 6;
        int g = (int)(idx & 63);
        u16x4 a = *reinterpret_cast<const u16x4*>(G1 + node * 256 + g * 4);
        u16x4 b = *reinterpret_cast<const u16x4*>(G2 + node * 256 + g * 4);
        f32x4 s1 = *reinterpret_cast<const f32x4*>(kp1 + g * 4);
        f32x4 t1 = *reinterpret_cast<const f32x4*>(kp1 + 256 + g * 4);
        f32x4 s2 = *reinterpret_cast<const f32x4*>(kp2 + g * 4);
        f32x4 t2 = *reinterpret_cast<const f32x4*>(kp2 + 256 + g * 4);
        float av[4], bv[4];
#pragma unroll
        for (int j = 0; j < 4; ++j) {
            av[j] = fmaxf(fmaf(bf2f(a[j]), s1[j], t1[j]), 0.f);
            bv[j] = fmaxf(fmaf(bf2f(b[j]), s2[j], t2[j]), 0.f);
        }
        int p0 = 0, p1 = 0;
        p0 = __builtin_amdgcn_cvt_pk_fp8_f32(av[0], av[1], p0, false);
        p0 = __builtin_amdgcn_cvt_pk_fp8_f32(av[2], av[3], p0, true);
        p1 = __builtin_amdgcn_cvt_pk_fp8_f32(bv[0], bv[1], p1, false);
        p1 = __builtin_amdgcn_cvt_pk_fp8_f32(bv[2], bv[3], p1, true);
        *reinterpret_cast<uint2*>(GG8 + node * 512 + g * 8) =
            make_uint2((unsigned int)p0, (unsigned int)p1);
    }
}

// single: O8[node][256] = f8(relu(bn(H)))
__global__ __launch_bounds__(256) void bnrelu1_f8_kernel(
    const unsigned short* __restrict__ H, const float* __restrict__ kp,
    unsigned char* __restrict__ O8, int N)
{
    long long total = (long long)N * 64;
    long long idx = (long long)blockIdx.x * blockDim.x + threadIdx.x;
    const long long stride = (long long)gridDim.x * blockDim.x;
    for (; idx < total; idx += stride) {
        long long node = idx >> 6;
        int g = (int)(idx & 63);
        u16x4 a = *reinterpret_cast<const u16x4*>(H + node * 256 + g * 4);
        f32x4 s = *reinterpret_cast<const f32x4*>(kp + g * 4);
        f32x4 t = *reinterpret_cast<const f32x4*>(kp + 256 + g * 4);
        float av[4];
#pragma unroll
        for (int j = 0; j < 4; ++j)
            av[j] = fmaxf(fmaf(bf2f(a[j]), s[j], t[j]), 0.f);
        int p0 = 0;
        p0 = __builtin_amdgcn_cvt_pk_fp8_f32(av[0], av[1], p0, false);
        p0 = __builtin_amdgcn_cvt_pk_fp8_f32(av[2], av[3], p0, true);
        *reinterpret_cast<unsigned int*>(O8 + node * 256 + g * 4) = (unsigned int)p0;
    }
}

// ---------------- SpMM 256-wide, pure gather of pre-activated fp8 ----------------
__global__ __launch_bounds__(256) void spmm256_kernel(
    const int* __restrict__ row_ptr, const unsigned int* __restrict__ meta,
    const unsigned char* __restrict__ S8, unsigned short* __restrict__ O, int N)
{
    const int wave = threadIdx.x >> 6;
    const int lane = threadIdx.x & 63;
    int node = blockIdx.x * 4 + wave;
    if (node >= N) return;
    node = __builtin_amdgcn_readfirstlane(node);
    const int beg = row_ptr[node];
    const int end = row_ptr[node + 1];
    float a0 = 0.f, a1 = 0.f, a2 = 0.f, a3 = 0.f;

    int e = beg;
    for (; e + 12 <= end; e += 12) {
        unsigned int m[12];
#pragma unroll
        for (int j = 0; j < 12; ++j) m[j] = meta[e + j];
        unsigned int v[12];
#pragma unroll
        for (int j = 0; j < 12; ++j)
            v[j] = *reinterpret_cast<const unsigned int*>(S8 + (size_t)(m[j] >> 8) * 256 + lane * 4);
#pragma unroll
        for (int j = 0; j < 12; ++j) {
            float w = meta_w(m[j]);
            f32x2 lo = __builtin_amdgcn_cvt_pk_f32_fp8(v[j], false);
            f32x2 hi = __builtin_amdgcn_cvt_pk_f32_fp8(v[j], true);
            a0 = fmaf(w, lo[0], a0);
            a1 = fmaf(w, lo[1], a1);
            a2 = fmaf(w, hi[0], a2);
            a3 = fmaf(w, hi[1], a3);
        }
    }
    for (; e < end; ++e) {
        unsigned int m = meta[e];
        float w = meta_w(m);
        unsigned int v = *reinterpret_cast<const unsigned int*>(S8 + (size_t)(m >> 8) * 256 + lane * 4);
        f32x2 lo = __builtin_amdgcn_cvt_pk_f32_fp8(v, false);
        f32x2 hi = __builtin_amdgcn_cvt_pk_f32_fp8(v, true);
        a0 = fmaf(w, lo[0], a0);
        a1 = fmaf(w, lo[1], a1);
        a2 = fmaf(w, hi[0], a2);
        a3 = fmaf(w, hi[1], a3);
    }
    u16x4 o;
    o[0] = f2bf(a0); o[1] = f2bf(a1); o[2] = f2bf(a2); o[3] = f2bf(a3);
    *reinterpret_cast<u16x4*>(O + (size_t)node * 256 + lane * 4) = o;
}

// ---------------- fused dual SpMM: one edge walk, ONE 8B load per edge (interleaved fp8) ----------------
__global__ __launch_bounds__(256) void spmm256x2_kernel(
    const int* __restrict__ row_ptr, const unsigned int* __restrict__ meta,
    const unsigned char* __restrict__ GG8,
    unsigned short* __restrict__ Oa, unsigned short* __restrict__ Ob, int N)
{
    const int wave = threadIdx.x >> 6;
    const int lane = threadIdx.x & 63;
    int node = blockIdx.x * 4 + wave;
    if (node >= N) return;
    node = __builtin_amdgcn_readfirstlane(node);
    const int beg = row_ptr[node];
    const int end = row_ptr[node + 1];
    float a0 = 0.f, a1 = 0.f, a2 = 0.f, a3 = 0.f;
    float b0 = 0.f, b1 = 0.f, b2 = 0.f, b3 = 0.f;

    int e = beg;
    for (; e + 10 <= end; e += 10) {
        unsigned int m[10];
#pragma unroll
        for (int j = 0; j < 10; ++j) m[j] = meta[e + j];
        uint2 v[10];
#pragma unroll
        for (int j = 0; j < 10; ++j)
            v[j] = *reinterpret_cast<const uint2*>(GG8 + (size_t)(m[j] >> 8) * 512 + lane * 8);
#pragma unroll
        for (int j = 0; j < 10; ++j) {
            float w = meta_w(m[j]);
            f32x2 alo = __builtin_amdgcn_cvt_pk_f32_fp8(v[j].x, false);
            f32x2 ahi = __builtin_amdgcn_cvt_pk_f32_fp8(v[j].x, true);
            f32x2 blo = __builtin_amdgcn_cvt_pk_f32_fp8(v[j].y, false);
            f32x2 bhi = __builtin_amdgcn_cvt_pk_f32_fp8(v[j].y, true);
            a0 = fmaf(w, alo[0], a0); a1 = fmaf(w, alo[1], a1);
            a2 = fmaf(w, ahi[0], a2); a3 = fmaf(w, ahi[1], a3);
            b0 = fmaf(w, blo[0], b0); b1 = fmaf(w, blo[1], b1);
            b2 = fmaf(w, bhi[0], b2); b3 = fmaf(w, bhi[1], b3);
        }
    }
    for (; e < end; ++e) {
        unsigned int m = meta[e];
        float w = meta_w(m);
        uint2 v = *reinterpret_cast<const uint2*>(GG8 + (size_t)(m >> 8) * 512 + lane * 8);
        f32x2 alo = __builtin_amdgcn_cvt_pk_f32_fp8(v.x, false);
        f32x2 ahi = __builtin_amdgcn_cvt_pk_f32_fp8(v.x, true);
        f32x2 blo = __builtin_amdgcn_cvt_pk_f32_fp8(v.y, false);
        f32x2 bhi = __builtin_amdgcn_cvt_pk_f32_fp8(v.y, true);
        a0 = fmaf(w, alo[0], a0); a1 = fmaf(w, alo[1], a1);
        a2 = fmaf(w, ahi[0], a2); a3 = fmaf(w, ahi[1], a3);
        b0 = fmaf(w, blo[0], b0); b1 = fmaf(w, blo[1], b1);
        b2 = fmaf(w, bhi[0], b2); b3 = fmaf(w, bhi[1], b3);
    }
    u16x4 oa, ob;
    oa[0] = f2bf(a0); oa[1] = f2bf(a1); oa[2] = f2bf(a2); oa[3] = f2bf(a3);
    ob[0] = f2bf(b0); ob[1] = f2bf(b1); ob[2] = f2bf(b2); ob[3] = f2bf(b3);
    *reinterpret_cast<u16x4*>(Oa + (size_t)node * 256 + lane * 4) = oa;
    *reinterpret_cast<u16x4*>(Ob + (size_t)node * 256 + lane * 4) = ob;
}

// ---------------- SpMM 512-wide, fp8 source: TWO waves per node, 8-deep ----------------
__global__ __launch_bounds__(512) void spmm512_kernel(
    const int* __restrict__ row_ptr, const unsigned int* __restrict__ meta,
    const unsigned char* __restrict__ S8, unsigned short* __restrict__ O, int N)
{
    const int wv = threadIdx.x >> 6;
    const int lane = threadIdx.x & 63;
    const int half = wv & 1;
    int node = blockIdx.x * 4 + (wv >> 1);
    if (node >= N) return;
    node = __builtin_amdgcn_readfirstlane(node);
    const int beg = row_ptr[node];
    const int end = row_ptr[node + 1];
    const int coff = half * 256 + lane * 4;
    float a0 = 0.f, a1 = 0.f, a2 = 0.f, a3 = 0.f;

    int e = beg;
    for (; e + 8 <= end; e += 8) {
        unsigned int m[8];
#pragma unroll
        for (int j = 0; j < 8; ++j) m[j] = meta[e + j];
        unsigned int v[8];
#pragma unroll
        for (int j = 0; j < 8; ++j)
            v[j] = *reinterpret_cast<const unsigned int*>(S8 + (size_t)(m[j] >> 8) * 512 + coff);
#pragma unroll
        for (int j = 0; j < 8; ++j) {
            float w = meta_w(m[j]);
            f32x2 lo = __builtin_amdgcn_cvt_pk_f32_fp8(v[j], false);
            f32x2 hi = __builtin_amdgcn_cvt_pk_f32_fp8(v[j], true);
            a0 = fmaf(w, lo[0], a0);
            a1 = fmaf(w, lo[1], a1);
            a2 = fmaf(w, hi[0], a2);
            a3 = fmaf(w, hi[1], a3);
        }
    }
    for (; e < end; ++e) {
        unsigned int m = meta[e];
        float w = meta_w(m);
        unsigned int v = *reinterpret_cast<const unsigned int*>(S8 + (size_t)(m >> 8) * 512 + coff);
        f32x2 lo = __builtin_amdgcn_cvt_pk_f32_fp8(v, false);
        f32x2 hi = __builtin_amdgcn_cvt_pk_f32_fp8(v, true);
        a0 = fmaf(w, lo[0], a0);
        a1 = fmaf(w, lo[1], a1);
        a2 = fmaf(w, hi[0], a2);
        a3 = fmaf(w, hi[1], a3);
    }
    u16x4 o;
    o[0] = f2bf(a0); o[1] = f2bf(a1); o[2] = f2bf(a2); o[3] = f2bf(a3);
    *reinterpret_cast<u16x4*>(O + (size_t)node * 512 + coff) = o;
}

// ---------------- LDS-staged MFMA GEMM ----------------
template<int K1, int K2, bool BN2>
__global__ __launch_bounds__(256) void gemm_lds_kernel(
    const unsigned short* __restrict__ A1, const unsigned short* __restrict__ A2,
    const float* __restrict__ kp, const unsigned short* __restrict__ Btf,
    const float* __restrict__ bias, unsigned short* __restrict__ Cout,
    float* __restrict__ stats, int N)
{
    constexpr int KT = K1 + K2;
    __shared__ unsigned short Atile[128 * 64];
    __shared__ unsigned short Btile[128 * 64];

    const int lane = threadIdx.x & 63;
    const int wave = threadIdx.x >> 6;
    const int l16 = lane & 15;
    const int khi = lane >> 4;
    const int wm = wave >> 1;
    const int wn = wave & 1;
    const long long bm = (long long)blockIdx.x * 128;
    const int col0 = blockIdx.y * 128;

    const int srow8 = lane >> 3;
    const int sc16 = lane & 7;

    f32x4 acc[4][4];
#pragma unroll
    for (int m = 0; m < 4; ++m)
#pragma unroll
        for (int n = 0; n < 4; ++n) acc[m][n] = (f32x4){0.f, 0.f, 0.f, 0.f};

    for (int k0 = 0; k0 < KT; k0 += 64) {
        const unsigned short* Aseg;
        int koff, astr;
        if (k0 < K1) { Aseg = A1; koff = k0; astr = K1; }
        else         { Aseg = A2; koff = k0 - K1; astr = K2; }
        const bool bnseg = BN2 && (k0 >= K1);

        u16x8 av[4], bv[4];
        int rloc[4];
#pragma unroll
        for (int i = 0; i < 4; ++i) {
            int r = wave * 32 + i * 8 + srow8;
            rloc[i] = r;
            long long gr = bm + r;
            if (gr >= N) gr = N - 1;
            av[i] = *reinterpret_cast<const u16x8*>(Aseg + (size_t)gr * astr + koff + sc16 * 8);
            bv[i] = *reinterpret_cast<const u16x8*>(Btf + (size_t)(col0 + r) * KT + k0 + sc16 * 8);
        }
        __syncthreads();
#pragma unroll
        for (int i = 0; i < 4; ++i) {
            int r = rloc[i];
            int cw = (sc16 ^ (r & 7)) * 8;
            *reinterpret_cast<u16x8*>(&Atile[r * 64 + cw]) = av[i];
            *reinterpret_cast<u16x8*>(&Btile[r * 64 + cw]) = bv[i];
        }
        __syncthreads();

#pragma unroll
        for (int kk = 0; kk < 2; ++kk) {
            const int kc = kk * 4 + khi;
            bf16x8 a[4], b[4];
#pragma unroll
            for (int m = 0; m < 4; ++m) {
                int ra = wm * 64 + m * 16 + l16;
                a[m] = *reinterpret_cast<const bf16x8*>(&Atile[ra * 64 + ((kc ^ (ra & 7)) * 8)]);
            }
            if (bnseg) {
                int ch = (k0 - K1) + kk * 32 + khi * 8;
                f32x4 s0 = *reinterpret_cast<const f32x4*>(kp + ch);
                f32x4 s1 = *reinterpret_cast<const f32x4*>(kp + ch + 4);
                f32x4 t0 = *reinterpret_cast<const f32x4*>(kp + 256 + ch);
                f32x4 t1 = *reinterpret_cast<const f32x4*>(kp + 256 + ch + 4);
#pragma unroll
                for (int m = 0; m < 4; ++m) {
                    u16x8 raw;
                    __builtin_memcpy(&raw, &a[m], 16);
                    u16x8 ov;
#pragma unroll
                    for (int j = 0; j < 4; ++j) {
                        ov[j]     = f2bf(fmaxf(fmaf(bf2f(raw[j]),     s0[j], t0[j]), 0.f));
                        ov[4 + j] = f2bf(fmaxf(fmaf(bf2f(raw[4 + j]), s1[j], t1[j]), 0.f));
                    }
                    __builtin_memcpy(&a[m], &ov, 16);
                }
            }
#pragma unroll
            for (int n = 0; n < 4; ++n) {
                int rb = wn * 64 + n * 16 + l16;
                b[n] = *reinterpret_cast<const bf16x8*>(&Btile[rb * 64 + ((kc ^ (rb & 7)) * 8)]);
            }
#pragma unroll
            for (int m = 0; m < 4; ++m)
#pragma unroll
                for (int n = 0; n < 4; ++n)
                    acc[m][n] = __builtin_amdgcn_mfma_f32_16x16x32_bf16(a[m], b[n], acc[m][n], 0, 0, 0);
        }
    }

    float bs[4];
#pragma unroll
    for (int n = 0; n < 4; ++n) bs[n] = bias[col0 + wn * 64 + n * 16 + l16];

    float s[4], s2[4];
#pragma unroll
    for (int n = 0; n < 4; ++n) { s[n] = 0.f; s2[n] = 0.f; }

#pragma unroll
    for (int m = 0; m < 4; ++m)
#pragma unroll
        for (int r = 0; r < 4; ++r) {
            long long grow = bm + wm * 64 + m * 16 + khi * 4 + r;
            if (grow >= N) continue;
#pragma unroll
            for (int n = 0; n < 4; ++n) {
                int gcol = col0 + wn * 64 + n * 16 + l16;
                float v = acc[m][n][r] + bs[n];
                Cout[grow * 256 + gcol] = f2bf(v);
                s[n] += v;
                s2[n] = fmaf(v, v, s2[n]);
            }
        }

#pragma unroll
    for (int n = 0; n < 4; ++n) {
        float a = s[n], b2 = s2[n];
        a += __shfl_xor(a, 16); a += __shfl_xor(a, 32);
        b2 += __shfl_xor(b2, 16); b2 += __shfl_xor(b2, 32);
        if (khi == 0) {
            int c = col0 + wn * 64 + n * 16 + l16;
            atomicAdd(&stats[c], a);
            atomicAdd(&stats[256 + c], b2);
        }
    }
}

// ---------------- BN finalize ----------------
__global__ __launch_bounds__(256) void bn_finalize_kernel(
    const float* __restrict__ sums, const float* __restrict__ g,
    const float* __restrict__ be, float* __restrict__ kp, int N)
{
    const int c = threadIdx.x;
    float invN = 1.f / (float)N;
    float mean = sums[c] * invN;
    float var = sums[256 + c] * invN - mean * mean;
    float inv = rsqrtf(var + 1e-5f);
    float sc = g[c] * inv;
    kp[c] = sc;
    kp[256 + c] = be[c] - sc * mean;
}

__global__ __launch_bounds__(256) void bn_finalize3_kernel(
    float* __restrict__ stats, const float* __restrict__ g,
    const float* __restrict__ be, int N)
{
    const int l = blockIdx.x;
    const int c = threadIdx.x;
    float* st = stats + (size_t)l * 1024;
    float invN = 1.f / (float)N;
    float mean = st[c] * invN;
    float var = st[256 + c] * invN - mean * mean;
    float inv = rsqrtf(var + 1e-5f);
    float sc = g[l * 256 + c] * inv;
    st[512 + c] = sc;
    st[768 + c] = be[l * 256 + c] - sc * mean;
}

// ---------------- final MFMA outproj ----------------
template<int KS, bool BN>
__device__ __forceinline__ void outproj_seg(
    const unsigned short* __restrict__ seg, const float* __restrict__ kp,
    const unsigned short* __restrict__ Wcb, int bOff,
    long long r0, long long r1, int l16, int khi, f32x4 acc[2][3])
{
    const unsigned short* a0p = seg + (size_t)r0 * KS + khi * 8;
    const unsigned short* a1p = seg + (size_t)r1 * KS + khi * 8;
#pragma unroll
    for (int k0 = 0; k0 < KS; k0 += 32) {
        bf16x8 a[2];
        a[0] = *reinterpret_cast<const bf16x8*>(a0p + k0);
        a[1] = *reinterpret_cast<const bf16x8*>(a1p + k0);
        if (BN) {
            int ch0 = k0 + khi * 8;
            f32x4 s0 = *reinterpret_cast<const f32x4*>(kp + ch0);
            f32x4 s1 = *reinterpret_cast<const f32x4*>(kp + ch0 + 4);
            f32x4 t0 = *reinterpret_cast<const f32x4*>(kp + 256 + ch0);
            f32x4 t1 = *reinterpret_cast<const f32x4*>(kp + 256 + ch0 + 4);
#pragma unroll
            for (int m = 0; m < 2; ++m) {
                u16x8 raw;
                __builtin_memcpy(&raw, &a[m], 16);
                u16x8 ov;
#pragma unroll
                for (int j = 0; j < 4; ++j) {
                    ov[j]     = f2bf(fmaxf(fmaf(bf2f(raw[j]),     s0[j], t0[j]), 0.f));
                    ov[4 + j] = f2bf(fmaxf(fmaf(bf2f(raw[4 + j]), s1[j], t1[j]), 0.f));
                }
                __builtin_memcpy(&a[m], &ov, 16);
            }
        }
        bf16x8 b[3];
#pragma unroll
        for (int nt = 0; nt < 3; ++nt)
            b[nt] = *reinterpret_cast<const bf16x8*>(Wcb + (size_t)(nt * 16 + l16) * 1280 + bOff + k0 + khi * 8);
#pragma unroll
        for (int m = 0; m < 2; ++m)
#pragma unroll
            for (int nt = 0; nt < 3; ++nt)
                acc[m][nt] = __builtin_amdgcn_mfma_f32_16x16x32_bf16(a[m], b[nt], acc[m][nt], 0, 0, 0);
    }
}

__global__ __launch_bounds__(256) void outproj_mfma_kernel(
    const unsigned short* __restrict__ x_bf,
    const unsigned short* __restrict__ F0, const float* __restrict__ kp0,
    const unsigned short* __restrict__ F1, const float* __restrict__ kp1,
    const unsigned short* __restrict__ F2, const float* __restrict__ kp2,
    const unsigned short* __restrict__ Wcb, const float* __restrict__ bc,
    float* __restrict__ out, int N)
{
    const int lane = threadIdx.x & 63;
    const int wave = threadIdx.x >> 6;
    const int l16 = lane & 15;
    const int khi = lane >> 4;
    const long long bm = (long long)blockIdx.x * 128 + wave * 32;

    long long r0 = bm + l16;        if (r0 >= N) r0 = 0;
    long long r1 = bm + 16 + l16;   if (r1 >= N) r1 = 0;

    f32x4 acc[2][3];
#pragma unroll
    for (int m = 0; m < 2; ++m)
#pragma unroll
        for (int nt = 0; nt < 3; ++nt) acc[m][nt] = (f32x4){0.f, 0.f, 0.f, 0.f};

    outproj_seg<512, false>(x_bf, nullptr, Wcb, 0,    r0, r1, l16, khi, acc);
    outproj_seg<256, true >(F0,   kp0,     Wcb, 512,  r0, r1, l16, khi, acc);
    outproj_seg<256, true >(F1,   kp1,     Wcb, 768,  r0, r1, l16, khi, acc);
    outproj_seg<256, true >(F2,   kp2,     Wcb, 1024, r0, r1, l16, khi, acc);

#pragma unroll
    for (int m = 0; m < 2; ++m)
#pragma unroll
        for (int nt = 0; nt < 3; ++nt)
#pragma unroll
            for (int r = 0; r < 4; ++r) {
                long long grow = bm + m * 16 + khi * 4 + r;
                int gcol = nt * 16 + l16;
                if (grow < N && gcol < 40)
                    out[grow * 40 + gcol] = acc[m][nt][r] + bc[gcol];
            }
}

// ---------------- host-side orchestration ----------------
extern "C" void kernel_launch(void* const* d_in, const int* in_sizes, int n_in,
                              void* d_out, int out_size, void* d_ws, size_t ws_size,
                              hipStream_t stream)
{
    const float* x      = (const float*)d_in[0];
    const int*   esrc   = (const int*)d_in[1];
    const int*   edst   = (const int*)d_in[2];
    const float* ew     = (const float*)d_in[3];
    const float* W_in   = (const float*)d_in[4];
    const float* SW_in  = (const float*)d_in[5];
    const float* b_in   = (const float*)d_in[6];
    const float* g_in   = (const float*)d_in[7];
    const float* be_in  = (const float*)d_in[8];
    const float* W_h    = (const float*)d_in[9];
    const float* SW_h   = (const float*)d_in[10];
    const float* b_h    = (const float*)d_in[11];
    const float* g_h    = (const float*)d_in[12];
    const float* be_h   = (const float*)d_in[13];
    const float* Wc     = (const float*)d_in[14];
    const float* bc     = (const float*)d_in[15];
    float* out = (float*)d_out;

    const int N = in_sizes[0] / 500;      // 100000
    const int n_edges = in_sizes[1];      // 3200000
    const int nb = (N + 255) / 256;
    const int nper = (N + 7) / 8;

    // ---- workspace layout ----
    char* p = (char*)d_ws;
    unsigned short* x_bf = (unsigned short*)p; p += (size_t)N * 512 * 2;
    unsigned short* Xa   = (unsigned short*)p; p += (size_t)N * 512 * 2;   // F2 aliases
    unsigned short* Ha   = (unsigned short*)p; p += (size_t)N * 256 * 2;
    unsigned short* Ha2  = (unsigned short*)p; p += (size_t)N * 256 * 2;
    unsigned short* G1   = (unsigned short*)p; p += (size_t)N * 256 * 2;   // H2 aliases
    unsigned short* G2   = (unsigned short*)p; p += (size_t)N * 256 * 2;
    unsigned short* F0   = (unsigned short*)p; p += (size_t)N * 256 * 2;
    unsigned short* F1   = (unsigned short*)p; p += (size_t)N * 256 * 2;
    unsigned short* H2   = G1;
    unsigned short* F2   = Xa;
    unsigned char* x_f8  = (unsigned char*)p; p += (size_t)N * 512;
    unsigned char* GG8   = (unsigned char*)p; p += (size_t)N * 512;  // interleaved bn-relu'd G1|G2
    unsigned char* H28   = GG8;   // alias: GG8 dead after dual spmm
    unsigned short* Wf_in = (unsigned short*)p; p += (size_t)3 * 256 * 1024 * 2;
    unsigned short* Wf_h  = (unsigned short*)p; p += (size_t)3 * 256 * 512 * 2;
    unsigned short* Wcb   = (unsigned short*)p; p += (size_t)48 * 1280 * 2;
    float* stats = (float*)p; p += (size_t)6 * 1024 * 4;
    int* cnt     = (int*)p; p += (size_t)N * 4;
    int* excl    = (int*)p; p += (size_t)N * 4;
    int* blocksums = (int*)p; p += 2048 * 4;
    int* row_ptr = (int*)p; p += (size_t)(N + 1) * 4 + 4;
    int* rank    = (int*)p; p += (size_t)n_edges * 4;
    unsigned int* meta = (unsigned int*)p;

    // ---- preprocessing ----
    hipMemsetAsync(stats, 0, (size_t)6 * 1024 * sizeof(float) + (size_t)N * sizeof(int), stream);
    hipLaunchKernelGGL(transpose_fused_kernel, dim3(2048), dim3(256), 0, stream,
                       W_in, SW_in, Wf_in, 500, 512, 3);
    hipLaunchKernelGGL(transpose_fused_kernel, dim3(1024), dim3(256), 0, stream,
                       W_h, SW_h, Wf_h, 256, 256, 3);
    hipLaunchKernelGGL(transpose_wc_kernel, dim3(240), dim3(256), 0, stream, Wc, Wcb);

    hipLaunchKernelGGL(hist_kernel, dim3(4096), dim3(256), 0, stream, edst, cnt, rank, n_edges);
    hipLaunchKernelGGL(scan1_kernel, dim3(nb), dim3(256), 0, stream, cnt, excl, blocksums, N);
    hipLaunchKernelGGL(scan2_kernel, dim3(1), dim3(512), 0, stream, blocksums, nb);
    hipLaunchKernelGGL(scan3_kernel, dim3(nb), dim3(256), 0, stream,
                       excl, blocksums, row_ptr, N, n_edges);
    hipLaunchKernelGGL(scatter_kernel, dim3(4096), dim3(256), 0, stream,
                       esrc, edst, ew, rank, row_ptr, meta, n_edges, nper);

    hipLaunchKernelGGL(cvtx_kernel, dim3(4096), dim3(256), 0, stream, x, x_bf, x_f8, N);

    hipLaunchKernelGGL(spmm512_kernel, dim3((N + 3) / 4), dim3(512), 0, stream,
                       row_ptr, meta, x_f8, Xa, N);

    dim3 blk(256);
    dim3 ggrid2((N + 127) / 128, 2);
    dim3 ogrid((N + 127) / 128);
    dim3 sgrid((N + 3) / 4);

    // ---- three input-layer GEMMs ----
    hipLaunchKernelGGL((gemm_lds_kernel<512, 512, false>), ggrid2, blk, 0, stream,
                       Xa, x_bf, (const float*)nullptr, Wf_in, b_in,
                       F0, stats + 0 * 1024, N);
    hipLaunchKernelGGL((gemm_lds_kernel<512, 512, false>), ggrid2, blk, 0, stream,
                       Xa, x_bf, (const float*)nullptr, Wf_in + (size_t)1 * 256 * 1024, b_in + 256,
                       G1, stats + 1 * 1024, N);
    hipLaunchKernelGGL((gemm_lds_kernel<512, 512, false>), ggrid2, blk, 0, stream,
                       Xa, x_bf, (const float*)nullptr, Wf_in + (size_t)2 * 256 * 1024, b_in + 512,
                       G2, stats + 2 * 1024, N);
    hipLaunchKernelGGL(bn_finalize3_kernel, dim3(3), dim3(256), 0, stream,
                       stats, g_in, be_in, N);

    float* kp0 = stats + 0 * 1024 + 512;
    float* kp1 = stats + 1 * 1024 + 512;
    float* kp2 = stats + 2 * 1024 + 512;
    float* st3 = stats + 3 * 1024;
    float* st4 = stats + 4 * 1024;
    float* st5 = stats + 5 * 1024;

    // ---- bn+relu fp8 interleave, then pure dual gather ----
    hipLaunchKernelGGL(bnrelu2_f8_kernel, dim3(2048), blk, 0, stream,
                       G1, kp1, G2, kp2, GG8, N);
    hipLaunchKernelGGL(spmm256x2_kernel, sgrid, blk, 0, stream,
                       row_ptr, meta, GG8, Ha, Ha2, N);

    // ---- j = 1: gemm -> F1 ----
    hipLaunchKernelGGL((gemm_lds_kernel<256, 256, true>), ggrid2, blk, 0, stream,
                       Ha, G1, kp1, Wf_h, b_h, F1, st3, N);
    hipLaunchKernelGGL(bn_finalize_kernel, dim3(1), dim3(256), 0, stream, st3, g_h, be_h, st3 + 512, N);

    // ---- j = 2: two hidden GCs ----
    hipLaunchKernelGGL((gemm_lds_kernel<256, 256, true>), ggrid2, blk, 0, stream,
                       Ha2, G2, kp2, Wf_h + (size_t)1 * 256 * 512, b_h + 256,
                       H2, st4, N);
    hipLaunchKernelGGL(bn_finalize_kernel, dim3(1), dim3(256), 0, stream, st4, g_h + 256, be_h + 256, st4 + 512, N);

    hipLaunchKernelGGL(bnrelu1_f8_kernel, dim3(2048), blk, 0, stream,
                       H2, st4 + 512, H28, N);
    hipLaunchKernelGGL(spmm256_kernel, sgrid, blk, 0, stream, row_ptr, meta, H28, Ha, N);
    hipLaunchKernelGGL((gemm_lds_kernel<256, 256, true>), ggrid2, blk, 0, stream,
                       Ha, H2, st4 + 512, Wf_h + (size_t)2 * 256 * 512, b_h + 512,
                       F2, st5, N);
    hipLaunchKernelGGL(bn_finalize_kernel, dim3(1), dim3(256), 0, stream, st5, g_h + 512, be_h + 512, st5 + 512, N);

    // ---- final outproj ----
    hipLaunchKernelGGL(outproj_mfma_kernel, ogrid, blk, 0, stream,
                       x_bf, F0, kp0, F1, st3 + 512, F2, st5 + 512,
                       Wcb, bc, out, N);
}

// Round 15
// 1719.447 us; speedup vs baseline: 1.4530x; 1.0277x over previous
//
#include <hip/hip_runtime.h>

typedef __attribute__((ext_vector_type(8))) short bf16x8;
typedef __attribute__((ext_vector_type(2))) float f32x2;
typedef __attribute__((ext_vector_type(4))) float f32x4;
typedef __attribute__((ext_vector_type(4))) unsigned short u16x4;
typedef __attribute__((ext_vector_type(8))) unsigned short u16x8;

__device__ __forceinline__ float bf2f(unsigned short u) {
    union { unsigned int i; float f; } v; v.i = ((unsigned int)u) << 16; return v.f;
}
__device__ __forceinline__ unsigned short f2bf(float f) {
    union { float f; unsigned int i; } v; v.f = f;
    unsigned int b = v.i;
    b += 0x7FFFu + ((b >> 16) & 1u);   // round-to-nearest-even
    return (unsigned short)(b >> 16);
}
__device__ __forceinline__ unsigned char f2f8(float f) {
    int p = __builtin_amdgcn_cvt_pk_fp8_f32(f, f, 0, false);
    return (unsigned char)(p & 0xFF);
}
// decode meta word: src = m >> 8, w = fp8(m & 0xFF) * 2^-5
__device__ __forceinline__ float meta_w(unsigned int m) {
    f32x2 lo = __builtin_amdgcn_cvt_pk_f32_fp8(m & 0xFFu, false);
    return lo[0] * 0.03125f;
}

// ---------------- fused weight transpose: W,SW [L][K][256] -> Wf[L][256][2*Kp] bf16 ----------------
__global__ __launch_bounds__(256) void transpose_fused_kernel(
    const float* __restrict__ W, const float* __restrict__ SW,
    unsigned short* __restrict__ Wf, int K, int Kp, int L)
{
    long long total = (long long)L * 256 * 2 * Kp;
    long long idx = (long long)blockIdx.x * blockDim.x + threadIdx.x;
    const long long stride = (long long)gridDim.x * blockDim.x;
    for (; idx < total; idx += stride) {
        int l = (int)(idx / ((long long)256 * 2 * Kp));
        long long rem = idx - (long long)l * 256 * 2 * Kp;
        int c = (int)(rem / (2 * Kp));
        int kk = (int)(rem - (long long)c * 2 * Kp);
        const float* src = (kk < Kp) ? W : SW;
        int k = (kk < Kp) ? kk : kk - Kp;
        float v = (k < K) ? src[((size_t)l * K + k) * 256 + c] : 0.f;
        Wf[idx] = f2bf(v);
    }
}

// ---------------- Wc[1268][40] fp32 -> Wcb[48][1280] bf16 ----------------
__global__ __launch_bounds__(256) void transpose_wc_kernel(
    const float* __restrict__ Wc, unsigned short* __restrict__ Wcb)
{
    int idx = blockIdx.x * blockDim.x + threadIdx.x;
    if (idx >= 48 * 1280) return;
    int c = idx / 1280;
    int kk = idx - c * 1280;
    int src = -1;
    if (kk < 512)       { if (kk < 500) src = kk; }
    else if (kk < 768)  src = 500 + (kk - 512);
    else if (kk < 1024) src = 756 + (kk - 768);
    else                src = 1012 + (kk - 1024);
    float v = (c < 40 && src >= 0) ? Wc[(size_t)src * 40 + c] : 0.f;
    Wcb[idx] = f2bf(v);
}

// ---------------- x -> bf16 [N][512] AND fp8 [N][512] ----------------
__global__ __launch_bounds__(256) void cvtx_kernel(
    const float* __restrict__ X, unsigned short* __restrict__ Xb,
    unsigned char* __restrict__ X8, int N)
{
    long long total = (long long)N * 64;
    long long idx = (long long)blockIdx.x * blockDim.x + threadIdx.x;
    const long long stride = (long long)gridDim.x * blockDim.x;
    for (; idx < total; idx += stride) {
        long long row = idx >> 6;
        int g = (int)(idx & 63);
        int k0 = g * 8;
        float v[8];
        if (k0 + 8 <= 500) {
            float4 q0 = *reinterpret_cast<const float4*>(X + row * 500 + k0);
            float4 q1 = *reinterpret_cast<const float4*>(X + row * 500 + k0 + 4);
            v[0] = q0.x; v[1] = q0.y; v[2] = q0.z; v[3] = q0.w;
            v[4] = q1.x; v[5] = q1.y; v[6] = q1.z; v[7] = q1.w;
        } else {
#pragma unroll
            for (int j = 0; j < 8; ++j) v[j] = (k0 + j < 500) ? X[row * 500 + k0 + j] : 0.f;
        }
        u16x8 o;
#pragma unroll
        for (int j = 0; j < 8; ++j) o[j] = f2bf(v[j]);
        *reinterpret_cast<u16x8*>(Xb + row * 512 + k0) = o;
        int p0 = 0, p1 = 0;
        p0 = __builtin_amdgcn_cvt_pk_fp8_f32(v[0], v[1], p0, false);
        p0 = __builtin_amdgcn_cvt_pk_fp8_f32(v[2], v[3], p0, true);
        p1 = __builtin_amdgcn_cvt_pk_fp8_f32(v[4], v[5], p1, false);
        p1 = __builtin_amdgcn_cvt_pk_fp8_f32(v[6], v[7], p1, true);
        uint2 pk = make_uint2((unsigned int)p0, (unsigned int)p1);
        *reinterpret_cast<uint2*>(X8 + row * 512 + k0) = pk;
    }
}

// ---------------- CSR build ----------------
__global__ __launch_bounds__(256) void hist_kernel(
    const int* __restrict__ edst, int* __restrict__ cnt,
    int* __restrict__ rank, int n_edges)
{
    int idx = blockIdx.x * blockDim.x + threadIdx.x;
    const int stride = gridDim.x * blockDim.x;
    for (; idx < n_edges; idx += stride)
        rank[idx] = atomicAdd(&cnt[edst[idx]], 1);
}

__global__ __launch_bounds__(256) void scan1_kernel(
    const int* __restrict__ cnt, int* __restrict__ excl,
    int* __restrict__ blocksums, int n)
{
    __shared__ int s[256];
    const int tid = threadIdx.x;
    const int i = blockIdx.x * 256 + tid;
    int v = (i < n) ? cnt[i] : 0;
    s[tid] = v;
    __syncthreads();
#pragma unroll
    for (int off = 1; off < 256; off <<= 1) {
        int t = s[tid];
        if (tid >= off) t += s[tid - off];
        __syncthreads();
        s[tid] = t;
        __syncthreads();
    }
    if (i < n) excl[i] = s[tid] - v;
    if (tid == 255) blocksums[blockIdx.x] = s[255];
}

__global__ __launch_bounds__(512) void scan2_kernel(int* __restrict__ blocksums, int nb)
{
    __shared__ int s[512];
    const int tid = threadIdx.x;
    int v = (tid < nb) ? blocksums[tid] : 0;
    s[tid] = v;
    __syncthreads();
#pragma unroll
    for (int off = 1; off < 512; off <<= 1) {
        int t = s[tid];
        if (tid >= off) t += s[tid - off];
        __syncthreads();
        s[tid] = t;
        __syncthreads();
    }
    if (tid < nb) blocksums[tid] = s[tid] - v;
}

__global__ __launch_bounds__(256) void scan3_kernel(
    const int* __restrict__ excl, const int* __restrict__ blocksums,
    int* __restrict__ row_ptr, int n, int n_edges)
{
    const int i = blockIdx.x * 256 + threadIdx.x;
    if (i < n)
        row_ptr[i] = excl[i] + blocksums[i >> 8];
    if (i == 0) row_ptr[n] = n_edges;
}

// ---------------- XCD-striped scatter: pos = row_ptr[dst] + rank, no atomics ----------------
__global__ __launch_bounds__(256) void scatter_kernel(
    const int* __restrict__ esrc, const int* __restrict__ edst,
    const float* __restrict__ ew, const int* __restrict__ rank,
    const int* __restrict__ row_ptr, unsigned int* __restrict__ meta,
    int n_edges, int nper)
{
    const int stripe = blockIdx.x & 7;
    const int lo = stripe * nper;
    const int hi = lo + nper;
    int idx = (blockIdx.x >> 3) * blockDim.x + threadIdx.x;
    const int stride = (gridDim.x >> 3) * blockDim.x;
    for (; idx < n_edges; idx += stride) {
        int d = edst[idx];
        if (d < lo || d >= hi) continue;
        int pos = row_ptr[d] + rank[idx];
        unsigned int m = ((unsigned int)esrc[idx] << 8) | f2f8(ew[idx] * 32.0f);
        meta[pos] = m;
    }
}

// ---------------- bn+relu -> fp8 converters ----------------
__global__ __launch_bounds__(256) void bnrelu2_f8_kernel(
    const unsigned short* __restrict__ G1, const float* __restrict__ kp1,
    const unsigned short* __restrict__ G2, const float* __restrict__ kp2,
    unsigned char* __restrict__ GG8, int N)
{
    long long total = (long long)N * 64;
    long long idx = (long long)blockIdx.x * blockDim.x + threadIdx.x;
    const long long stride = (long long)gridDim.x * blockDim.x;
    for (; idx < total; idx += stride) {
        long long node = idx >> 6;
        int g = (int)(idx & 63);
        u16x4 a = *reinterpret_cast<const u16x4*>(G1 + node * 256 + g * 4);
        u16x4 b = *reinterpret_cast<const u16x4*>(G2 + node * 256 + g * 4);
        f32x4 s1 = *reinterpret_cast<const f32x4*>(kp1 + g * 4);
        f32x4 t1 = *reinterpret_cast<const f32x4*>(kp1 + 256 + g * 4);
        f32x4 s2 = *reinterpret_cast<const f32x4*>(kp2 + g * 4);
        f32x4 t2 = *reinterpret_cast<const f32x4*>(kp2 + 256 + g * 4);
        float av[4], bv[4];
#pragma unroll
        for (int j = 0; j < 4; ++j) {
            av[j] = fmaxf(fmaf(bf2f(a[j]), s1[j], t1[j]), 0.f);
            bv[j] = fmaxf(fmaf(bf2f(b[j]), s2[j], t2[j]), 0.f);
        }
        int p0 = 0, p1 = 0;
        p0 = __builtin_amdgcn_cvt_pk_fp8_f32(av[0], av[1], p0, false);
        p0 = __builtin_amdgcn_cvt_pk_fp8_f32(av[2], av[3], p0, true);
        p1 = __builtin_amdgcn_cvt_pk_fp8_f32(bv[0], bv[1], p1, false);
        p1 = __builtin_amdgcn_cvt_pk_fp8_f32(bv[2], bv[3], p1, true);
        *reinterpret_cast<uint2*>(GG8 + node * 512 + g * 8) =
            make_uint2((unsigned int)p0, (unsigned int)p1);
    }
}

__global__ __launch_bounds__(256) void bnrelu1_f8_kernel(
    const unsigned short* __restrict__ H, const float* __restrict__ kp,
    unsigned char* __restrict__ O8, int N)
{
    long long total = (long long)N * 64;
    long long idx = (long long)blockIdx.x * blockDim.x + threadIdx.x;
    const long long stride = (long long)gridDim.x * blockDim.x;
    for (; idx < total; idx += stride) {
        long long node = idx >> 6;
        int g = (int)(idx & 63);
        u16x4 a = *reinterpret_cast<const u16x4*>(H + node * 256 + g * 4);
        f32x4 s = *reinterpret_cast<const f32x4*>(kp + g * 4);
        f32x4 t = *reinterpret_cast<const f32x4*>(kp + 256 + g * 4);
        float av[4];
#pragma unroll
        for (int j = 0; j < 4; ++j)
            av[j] = fmaxf(fmaf(bf2f(a[j]), s[j], t[j]), 0.f);
        int p0 = 0;
        p0 = __builtin_amdgcn_cvt_pk_fp8_f32(av[0], av[1], p0, false);
        p0 = __builtin_amdgcn_cvt_pk_fp8_f32(av[2], av[3], p0, true);
        *reinterpret_cast<unsigned int*>(O8 + node * 256 + g * 4) = (unsigned int)p0;
    }
}

// ---------------- SpMM 256-wide, pure gather of pre-activated fp8 ----------------
__global__ __launch_bounds__(256) void spmm256_kernel(
    const int* __restrict__ row_ptr, const unsigned int* __restrict__ meta,
    const unsigned char* __restrict__ S8, unsigned short* __restrict__ O, int N)
{
    const int wave = threadIdx.x >> 6;
    const int lane = threadIdx.x & 63;
    int node = blockIdx.x * 4 + wave;
    if (node >= N) return;
    node = __builtin_amdgcn_readfirstlane(node);
    const int beg = row_ptr[node];
    const int end = row_ptr[node + 1];
    float a0 = 0.f, a1 = 0.f, a2 = 0.f, a3 = 0.f;

    int e = beg;
    for (; e + 12 <= end; e += 12) {
        unsigned int m[12];
#pragma unroll
        for (int j = 0; j < 12; ++j) m[j] = meta[e + j];
        unsigned int v[12];
#pragma unroll
        for (int j = 0; j < 12; ++j)
            v[j] = *reinterpret_cast<const unsigned int*>(S8 + (size_t)(m[j] >> 8) * 256 + lane * 4);
#pragma unroll
        for (int j = 0; j < 12; ++j) {
            float w = meta_w(m[j]);
            f32x2 lo = __builtin_amdgcn_cvt_pk_f32_fp8(v[j], false);
            f32x2 hi = __builtin_amdgcn_cvt_pk_f32_fp8(v[j], true);
            a0 = fmaf(w, lo[0], a0);
            a1 = fmaf(w, lo[1], a1);
            a2 = fmaf(w, hi[0], a2);
            a3 = fmaf(w, hi[1], a3);
        }
    }
    for (; e < end; ++e) {
        unsigned int m = meta[e];
        float w = meta_w(m);
        unsigned int v = *reinterpret_cast<const unsigned int*>(S8 + (size_t)(m >> 8) * 256 + lane * 4);
        f32x2 lo = __builtin_amdgcn_cvt_pk_f32_fp8(v, false);
        f32x2 hi = __builtin_amdgcn_cvt_pk_f32_fp8(v, true);
        a0 = fmaf(w, lo[0], a0);
        a1 = fmaf(w, lo[1], a1);
        a2 = fmaf(w, hi[0], a2);
        a3 = fmaf(w, hi[1], a3);
    }
    u16x4 o;
    o[0] = f2bf(a0); o[1] = f2bf(a1); o[2] = f2bf(a2); o[3] = f2bf(a3);
    *reinterpret_cast<u16x4*>(O + (size_t)node * 256 + lane * 4) = o;
}

// ---------------- fused dual SpMM: one edge walk, ONE 8B load per edge ----------------
__global__ __launch_bounds__(256) void spmm256x2_kernel(
    const int* __restrict__ row_ptr, const unsigned int* __restrict__ meta,
    const unsigned char* __restrict__ GG8,
    unsigned short* __restrict__ Oa, unsigned short* __restrict__ Ob, int N)
{
    const int wave = threadIdx.x >> 6;
    const int lane = threadIdx.x & 63;
    int node = blockIdx.x * 4 + wave;
    if (node >= N) return;
    node = __builtin_amdgcn_readfirstlane(node);
    const int beg = row_ptr[node];
    const int end = row_ptr[node + 1];
    float a0 = 0.f, a1 = 0.f, a2 = 0.f, a3 = 0.f;
    float b0 = 0.f, b1 = 0.f, b2 = 0.f, b3 = 0.f;

    int e = beg;
    for (; e + 10 <= end; e += 10) {
        unsigned int m[10];
#pragma unroll
        for (int j = 0; j < 10; ++j) m[j] = meta[e + j];
        uint2 v[10];
#pragma unroll
        for (int j = 0; j < 10; ++j)
            v[j] = *reinterpret_cast<const uint2*>(GG8 + (size_t)(m[j] >> 8) * 512 + lane * 8);
#pragma unroll
        for (int j = 0; j < 10; ++j) {
            float w = meta_w(m[j]);
            f32x2 alo = __builtin_amdgcn_cvt_pk_f32_fp8(v[j].x, false);
            f32x2 ahi = __builtin_amdgcn_cvt_pk_f32_fp8(v[j].x, true);
            f32x2 blo = __builtin_amdgcn_cvt_pk_f32_fp8(v[j].y, false);
            f32x2 bhi = __builtin_amdgcn_cvt_pk_f32_fp8(v[j].y, true);
            a0 = fmaf(w, alo[0], a0); a1 = fmaf(w, alo[1], a1);
            a2 = fmaf(w, ahi[0], a2); a3 = fmaf(w, ahi[1], a3);
            b0 = fmaf(w, blo[0], b0); b1 = fmaf(w, blo[1], b1);
            b2 = fmaf(w, bhi[0], b2); b3 = fmaf(w, bhi[1], b3);
        }
    }
    for (; e < end; ++e) {
        unsigned int m = meta[e];
        float w = meta_w(m);
        uint2 v = *reinterpret_cast<const uint2*>(GG8 + (size_t)(m >> 8) * 512 + lane * 8);
        f32x2 alo = __builtin_amdgcn_cvt_pk_f32_fp8(v.x, false);
        f32x2 ahi = __builtin_amdgcn_cvt_pk_f32_fp8(v.x, true);
        f32x2 blo = __builtin_amdgcn_cvt_pk_f32_fp8(v.y, false);
        f32x2 bhi = __builtin_amdgcn_cvt_pk_f32_fp8(v.y, true);
        a0 = fmaf(w, alo[0], a0); a1 = fmaf(w, alo[1], a1);
        a2 = fmaf(w, ahi[0], a2); a3 = fmaf(w, ahi[1], a3);
        b0 = fmaf(w, blo[0], b0); b1 = fmaf(w, blo[1], b1);
        b2 = fmaf(w, bhi[0], b2); b3 = fmaf(w, bhi[1], b3);
    }
    u16x4 oa, ob;
    oa[0] = f2bf(a0); oa[1] = f2bf(a1); oa[2] = f2bf(a2); oa[3] = f2bf(a3);
    ob[0] = f2bf(b0); ob[1] = f2bf(b1); ob[2] = f2bf(b2); ob[3] = f2bf(b3);
    *reinterpret_cast<u16x4*>(Oa + (size_t)node * 256 + lane * 4) = oa;
    *reinterpret_cast<u16x4*>(Ob + (size_t)node * 256 + lane * 4) = ob;
}

// ---------------- SpMM 512-wide, fp8 source: TWO waves per node, 12-deep ----------------
__global__ __launch_bounds__(512) void spmm512_kernel(
    const int* __restrict__ row_ptr, const unsigned int* __restrict__ meta,
    const unsigned char* __restrict__ S8, unsigned short* __restrict__ O, int N)
{
    const int wv = threadIdx.x >> 6;
    const int lane = threadIdx.x & 63;
    const int half = wv & 1;
    int node = blockIdx.x * 4 + (wv >> 1);
    if (node >= N) return;
    node = __builtin_amdgcn_readfirstlane(node);
    const int beg = row_ptr[node];
    const int end = row_ptr[node + 1];
    const int coff = half * 256 + lane * 4;
    float a0 = 0.f, a1 = 0.f, a2 = 0.f, a3 = 0.f;

    int e = beg;
    for (; e + 12 <= end; e += 12) {
        unsigned int m[12];
#pragma unroll
        for (int j = 0; j < 12; ++j) m[j] = meta[e + j];
        unsigned int v[12];
#pragma unroll
        for (int j = 0; j < 12; ++j)
            v[j] = *reinterpret_cast<const unsigned int*>(S8 + (size_t)(m[j] >> 8) * 512 + coff);
#pragma unroll
        for (int j = 0; j < 12; ++j) {
            float w = meta_w(m[j]);
            f32x2 lo = __builtin_amdgcn_cvt_pk_f32_fp8(v[j], false);
            f32x2 hi = __builtin_amdgcn_cvt_pk_f32_fp8(v[j], true);
            a0 = fmaf(w, lo[0], a0);
            a1 = fmaf(w, lo[1], a1);
            a2 = fmaf(w, hi[0], a2);
            a3 = fmaf(w, hi[1], a3);
        }
    }
    for (; e + 4 <= end; e += 4) {
        unsigned int m[4];
#pragma unroll
        for (int j = 0; j < 4; ++j) m[j] = meta[e + j];
        unsigned int v[4];
#pragma unroll
        for (int j = 0; j < 4; ++j)
            v[j] = *reinterpret_cast<const unsigned int*>(S8 + (size_t)(m[j] >> 8) * 512 + coff);
#pragma unroll
        for (int j = 0; j < 4; ++j) {
            float w = meta_w(m[j]);
            f32x2 lo = __builtin_amdgcn_cvt_pk_f32_fp8(v[j], false);
            f32x2 hi = __builtin_amdgcn_cvt_pk_f32_fp8(v[j], true);
            a0 = fmaf(w, lo[0], a0);
            a1 = fmaf(w, lo[1], a1);
            a2 = fmaf(w, hi[0], a2);
            a3 = fmaf(w, hi[1], a3);
        }
    }
    for (; e < end; ++e) {
        unsigned int m = meta[e];
        float w = meta_w(m);
        unsigned int v = *reinterpret_cast<const unsigned int*>(S8 + (size_t)(m >> 8) * 512 + coff);
        f32x2 lo = __builtin_amdgcn_cvt_pk_f32_fp8(v, false);
        f32x2 hi = __builtin_amdgcn_cvt_pk_f32_fp8(v, true);
        a0 = fmaf(w, lo[0], a0);
        a1 = fmaf(w, lo[1], a1);
        a2 = fmaf(w, hi[0], a2);
        a3 = fmaf(w, hi[1], a3);
    }
    u16x4 o;
    o[0] = f2bf(a0); o[1] = f2bf(a1); o[2] = f2bf(a2); o[3] = f2bf(a3);
    *reinterpret_cast<u16x4*>(O + (size_t)node * 512 + coff) = o;
}

// ---------------- LDS-staged MFMA GEMM, software-pipelined staging ----------------
// Loads for tile k+1 are issued BEFORE compute of tile k (HBM latency hides under MFMA).
template<int K1, int K2, bool BN2>
__global__ __launch_bounds__(256) void gemm_lds_kernel(
    const unsigned short* __restrict__ A1, const unsigned short* __restrict__ A2,
    const float* __restrict__ kp, const unsigned short* __restrict__ Btf,
    const float* __restrict__ bias, unsigned short* __restrict__ Cout,
    float* __restrict__ stats, int N)
{
    constexpr int KT = K1 + K2;
    __shared__ unsigned short Atile[128 * 64];
    __shared__ unsigned short Btile[128 * 64];

    const int lane = threadIdx.x & 63;
    const int wave = threadIdx.x >> 6;
    const int l16 = lane & 15;
    const int khi = lane >> 4;
    const int wm = wave >> 1;
    const int wn = wave & 1;
    const long long bm = (long long)blockIdx.x * 128;
    const int col0 = blockIdx.y * 128;

    const int srow8 = lane >> 3;
    const int sc16 = lane & 7;

    // per-thread staging rows (fixed across k-tiles)
    int rloc[4];
    long long grow_[4];
#pragma unroll
    for (int i = 0; i < 4; ++i) {
        int r = wave * 32 + i * 8 + srow8;
        rloc[i] = r;
        long long gr = bm + r;
        if (gr >= N) gr = N - 1;
        grow_[i] = gr;
    }

    f32x4 acc[4][4];
#pragma unroll
    for (int m = 0; m < 4; ++m)
#pragma unroll
        for (int n = 0; n < 4; ++n) acc[m][n] = (f32x4){0.f, 0.f, 0.f, 0.f};

    u16x8 av[4], bv[4];
    auto issue_loads = [&](int kq) {
        const unsigned short* Aseg;
        int koff, astr;
        if (kq < K1) { Aseg = A1; koff = kq; astr = K1; }
        else         { Aseg = A2; koff = kq - K1; astr = K2; }
#pragma unroll
        for (int i = 0; i < 4; ++i) {
            av[i] = *reinterpret_cast<const u16x8*>(Aseg + (size_t)grow_[i] * astr + koff + sc16 * 8);
            bv[i] = *reinterpret_cast<const u16x8*>(Btf + (size_t)(col0 + rloc[i]) * KT + kq + sc16 * 8);
        }
    };

    issue_loads(0);   // prologue

    for (int k0 = 0; k0 < KT; k0 += 64) {
        __syncthreads();   // previous tile's LDS readers done
#pragma unroll
        for (int i = 0; i < 4; ++i) {
            int r = rloc[i];
            int cw = (sc16 ^ (r & 7)) * 8;
            *reinterpret_cast<u16x8*>(&Atile[r * 64 + cw]) = av[i];
            *reinterpret_cast<u16x8*>(&Btile[r * 64 + cw]) = bv[i];
        }
        __syncthreads();   // tile k0 ready in LDS

        if (k0 + 64 < KT) issue_loads(k0 + 64);   // prefetch next tile (in flight during compute)

        const bool bnseg = BN2 && (k0 >= K1);
#pragma unroll
        for (int kk = 0; kk < 2; ++kk) {
            const int kc = kk * 4 + khi;
            bf16x8 a[4], b[4];
#pragma unroll
            for (int m = 0; m < 4; ++m) {
                int ra = wm * 64 + m * 16 + l16;
                a[m] = *reinterpret_cast<const bf16x8*>(&Atile[ra * 64 + ((kc ^ (ra & 7)) * 8)]);
            }
            if (bnseg) {
                int ch = (k0 - K1) + kk * 32 + khi * 8;
                f32x4 s0 = *reinterpret_cast<const f32x4*>(kp + ch);
                f32x4 s1 = *reinterpret_cast<const f32x4*>(kp + ch + 4);
                f32x4 t0 = *reinterpret_cast<const f32x4*>(kp + 256 + ch);
                f32x4 t1 = *reinterpret_cast<const f32x4*>(kp + 256 + ch + 4);
#pragma unroll
                for (int m = 0; m < 4; ++m) {
                    u16x8 raw;
                    __builtin_memcpy(&raw, &a[m], 16);
                    u16x8 ov;
#pragma unroll
                    for (int j = 0; j < 4; ++j) {
                        ov[j]     = f2bf(fmaxf(fmaf(bf2f(raw[j]),     s0[j], t0[j]), 0.f));
                        ov[4 + j] = f2bf(fmaxf(fmaf(bf2f(raw[4 + j]), s1[j], t1[j]), 0.f));
                    }
                    __builtin_memcpy(&a[m], &ov, 16);
                }
            }
#pragma unroll
            for (int n = 0; n < 4; ++n) {
                int rb = wn * 64 + n * 16 + l16;
                b[n] = *reinterpret_cast<const bf16x8*>(&Btile[rb * 64 + ((kc ^ (rb & 7)) * 8)]);
            }
#pragma unroll
            for (int m = 0; m < 4; ++m)
#pragma unroll
                for (int n = 0; n < 4; ++n)
                    acc[m][n] = __builtin_amdgcn_mfma_f32_16x16x32_bf16(a[m], b[n], acc[m][n], 0, 0, 0);
        }
    }

    float bs[4];
#pragma unroll
    for (int n = 0; n < 4; ++n) bs[n] = bias[col0 + wn * 64 + n * 16 + l16];

    float s[4], s2[4];
#pragma unroll
    for (int n = 0; n < 4; ++n) { s[n] = 0.f; s2[n] = 0.f; }

#pragma unroll
    for (int m = 0; m < 4; ++m)
#pragma unroll
        for (int r = 0; r < 4; ++r) {
            long long grow = bm + wm * 64 + m * 16 + khi * 4 + r;
            if (grow >= N) continue;
#pragma unroll
            for (int n = 0; n < 4; ++n) {
                int gcol = col0 + wn * 64 + n * 16 + l16;
                float v = acc[m][n][r] + bs[n];
                Cout[grow * 256 + gcol] = f2bf(v);
                s[n] += v;
                s2[n] = fmaf(v, v, s2[n]);
            }
        }

#pragma unroll
    for (int n = 0; n < 4; ++n) {
        float a = s[n], b2 = s2[n];
        a += __shfl_xor(a, 16); a += __shfl_xor(a, 32);
        b2 += __shfl_xor(b2, 16); b2 += __shfl_xor(b2, 32);
        if (khi == 0) {
            int c = col0 + wn * 64 + n * 16 + l16;
            atomicAdd(&stats[c], a);
            atomicAdd(&stats[256 + c], b2);
        }
    }
}

// ---------------- BN finalize ----------------
__global__ __launch_bounds__(256) void bn_finalize_kernel(
    const float* __restrict__ sums, const float* __restrict__ g,
    const float* __restrict__ be, float* __restrict__ kp, int N)
{
    const int c = threadIdx.x;
    float invN = 1.f / (float)N;
    float mean = sums[c] * invN;
    float var = sums[256 + c] * invN - mean * mean;
    float inv = rsqrtf(var + 1e-5f);
    float sc = g[c] * inv;
    kp[c] = sc;
    kp[256 + c] = be[c] - sc * mean;
}

__global__ __launch_bounds__(256) void bn_finalize3_kernel(
    float* __restrict__ stats, const float* __restrict__ g,
    const float* __restrict__ be, int N)
{
    const int l = blockIdx.x;
    const int c = threadIdx.x;
    float* st = stats + (size_t)l * 1024;
    float invN = 1.f / (float)N;
    float mean = st[c] * invN;
    float var = st[256 + c] * invN - mean * mean;
    float inv = rsqrtf(var + 1e-5f);
    float sc = g[l * 256 + c] * inv;
    st[512 + c] = sc;
    st[768 + c] = be[l * 256 + c] - sc * mean;
}

// ---------------- final MFMA outproj ----------------
template<int KS, bool BN>
__device__ __forceinline__ void outproj_seg(
    const unsigned short* __restrict__ seg, const float* __restrict__ kp,
    const unsigned short* __restrict__ Wcb, int bOff,
    long long r0, long long r1, int l16, int khi, f32x4 acc[2][3])
{
    const unsigned short* a0p = seg + (size_t)r0 * KS + khi * 8;
    const unsigned short* a1p = seg + (size_t)r1 * KS + khi * 8;
#pragma unroll
    for (int k0 = 0; k0 < KS; k0 += 32) {
        bf16x8 a[2];
        a[0] = *reinterpret_cast<const bf16x8*>(a0p + k0);
        a[1] = *reinterpret_cast<const bf16x8*>(a1p + k0);
        if (BN) {
            int ch0 = k0 + khi * 8;
            f32x4 s0 = *reinterpret_cast<const f32x4*>(kp + ch0);
            f32x4 s1 = *reinterpret_cast<const f32x4*>(kp + ch0 + 4);
            f32x4 t0 = *reinterpret_cast<const f32x4*>(kp + 256 + ch0);
            f32x4 t1 = *reinterpret_cast<const f32x4*>(kp + 256 + ch0 + 4);
#pragma unroll
            for (int m = 0; m < 2; ++m) {
                u16x8 raw;
                __builtin_memcpy(&raw, &a[m], 16);
                u16x8 ov;
#pragma unroll
                for (int j = 0; j < 4; ++j) {
                    ov[j]     = f2bf(fmaxf(fmaf(bf2f(raw[j]),     s0[j], t0[j]), 0.f));
                    ov[4 + j] = f2bf(fmaxf(fmaf(bf2f(raw[4 + j]), s1[j], t1[j]), 0.f));
                }
                __builtin_memcpy(&a[m], &ov, 16);
            }
        }
        bf16x8 b[3];
#pragma unroll
        for (int nt = 0; nt < 3; ++nt)
            b[nt] = *reinterpret_cast<const bf16x8*>(Wcb + (size_t)(nt * 16 + l16) * 1280 + bOff + k0 + khi * 8);
#pragma unroll
        for (int m = 0; m < 2; ++m)
#pragma unroll
            for (int nt = 0; nt < 3; ++nt)
                acc[m][nt] = __builtin_amdgcn_mfma_f32_16x16x32_bf16(a[m], b[nt], acc[m][nt], 0, 0, 0);
    }
}

__global__ __launch_bounds__(256) void outproj_mfma_kernel(
    const unsigned short* __restrict__ x_bf,
    const unsigned short* __restrict__ F0, const float* __restrict__ kp0,
    const unsigned short* __restrict__ F1, const float* __restrict__ kp1,
    const unsigned short* __restrict__ F2, const float* __restrict__ kp2,
    const unsigned short* __restrict__ Wcb, const float* __restrict__ bc,
    float* __restrict__ out, int N)
{
    const int lane = threadIdx.x & 63;
    const int wave = threadIdx.x >> 6;
    const int l16 = lane & 15;
    const int khi = lane >> 4;
    const long long bm = (long long)blockIdx.x * 128 + wave * 32;

    long long r0 = bm + l16;        if (r0 >= N) r0 = 0;
    long long r1 = bm + 16 + l16;   if (r1 >= N) r1 = 0;

    f32x4 acc[2][3];
#pragma unroll
    for (int m = 0; m < 2; ++m)
#pragma unroll
        for (int nt = 0; nt < 3; ++nt) acc[m][nt] = (f32x4){0.f, 0.f, 0.f, 0.f};

    outproj_seg<512, false>(x_bf, nullptr, Wcb, 0,    r0, r1, l16, khi, acc);
    outproj_seg<256, true >(F0,   kp0,     Wcb, 512,  r0, r1, l16, khi, acc);
    outproj_seg<256, true >(F1,   kp1,     Wcb, 768,  r0, r1, l16, khi, acc);
    outproj_seg<256, true >(F2,   kp2,     Wcb, 1024, r0, r1, l16, khi, acc);

#pragma unroll
    for (int m = 0; m < 2; ++m)
#pragma unroll
        for (int nt = 0; nt < 3; ++nt)
#pragma unroll
            for (int r = 0; r < 4; ++r) {
                long long grow = bm + m * 16 + khi * 4 + r;
                int gcol = nt * 16 + l16;
                if (grow < N && gcol < 40)
                    out[grow * 40 + gcol] = acc[m][nt][r] + bc[gcol];
            }
}

// ---------------- host-side orchestration ----------------
extern "C" void kernel_launch(void* const* d_in, const int* in_sizes, int n_in,
                              void* d_out, int out_size, void* d_ws, size_t ws_size,
                              hipStream_t stream)
{
    const float* x      = (const float*)d_in[0];
    const int*   esrc   = (const int*)d_in[1];
    const int*   edst   = (const int*)d_in[2];
    const float* ew     = (const float*)d_in[3];
    const float* W_in   = (const float*)d_in[4];
    const float* SW_in  = (const float*)d_in[5];
    const float* b_in   = (const float*)d_in[6];
    const float* g_in   = (const float*)d_in[7];
    const float* be_in  = (const float*)d_in[8];
    const float* W_h    = (const float*)d_in[9];
    const float* SW_h   = (const float*)d_in[10];
    const float* b_h    = (const float*)d_in[11];
    const float* g_h    = (const float*)d_in[12];
    const float* be_h   = (const float*)d_in[13];
    const float* Wc     = (const float*)d_in[14];
    const float* bc     = (const float*)d_in[15];
    float* out = (float*)d_out;

    const int N = in_sizes[0] / 500;      // 100000
    const int n_edges = in_sizes[1];      // 3200000
    const int nb = (N + 255) / 256;
    const int nper = (N + 7) / 8;

    // ---- workspace layout ----
    char* p = (char*)d_ws;
    unsigned short* x_bf = (unsigned short*)p; p += (size_t)N * 512 * 2;
    unsigned short* Xa   = (unsigned short*)p; p += (size_t)N * 512 * 2;   // F2 aliases
    unsigned short* Ha   = (unsigned short*)p; p += (size_t)N * 256 * 2;
    unsigned short* Ha2  = (unsigned short*)p; p += (size_t)N * 256 * 2;
    unsigned short* G1   = (unsigned short*)p; p += (size_t)N * 256 * 2;   // H2 aliases
    unsigned short* G2   = (unsigned short*)p; p += (size_t)N * 256 * 2;
    unsigned short* F0   = (unsigned short*)p; p += (size_t)N * 256 * 2;
    unsigned short* F1   = (unsigned short*)p; p += (size_t)N * 256 * 2;
    unsigned short* H2   = G1;
    unsigned short* F2   = Xa;
    unsigned char* x_f8  = (unsigned char*)p; p += (size_t)N * 512;
    unsigned char* GG8   = (unsigned char*)p; p += (size_t)N * 512;  // interleaved bn-relu'd G1|G2
    unsigned char* H28   = GG8;   // alias: GG8 dead after dual spmm
    unsigned short* Wf_in = (unsigned short*)p; p += (size_t)3 * 256 * 1024 * 2;
    unsigned short* Wf_h  = (unsigned short*)p; p += (size_t)3 * 256 * 512 * 2;
    unsigned short* Wcb   = (unsigned short*)p; p += (size_t)48 * 1280 * 2;
    float* stats = (float*)p; p += (size_t)6 * 1024 * 4;
    int* cnt     = (int*)p; p += (size_t)N * 4;
    int* excl    = (int*)p; p += (size_t)N * 4;
    int* blocksums = (int*)p; p += 2048 * 4;
    int* row_ptr = (int*)p; p += (size_t)(N + 1) * 4 + 4;
    int* rank    = (int*)p; p += (size_t)n_edges * 4;
    unsigned int* meta = (unsigned int*)p;

    // ---- preprocessing ----
    hipMemsetAsync(stats, 0, (size_t)6 * 1024 * sizeof(float) + (size_t)N * sizeof(int), stream);
    hipLaunchKernelGGL(transpose_fused_kernel, dim3(2048), dim3(256), 0, stream,
                       W_in, SW_in, Wf_in, 500, 512, 3);
    hipLaunchKernelGGL(transpose_fused_kernel, dim3(1024), dim3(256), 0, stream,
                       W_h, SW_h, Wf_h, 256, 256, 3);
    hipLaunchKernelGGL(transpose_wc_kernel, dim3(240), dim3(256), 0, stream, Wc, Wcb);

    hipLaunchKernelGGL(hist_kernel, dim3(4096), dim3(256), 0, stream, edst, cnt, rank, n_edges);
    hipLaunchKernelGGL(scan1_kernel, dim3(nb), dim3(256), 0, stream, cnt, excl, blocksums, N);
    hipLaunchKernelGGL(scan2_kernel, dim3(1), dim3(512), 0, stream, blocksums, nb);
    hipLaunchKernelGGL(scan3_kernel, dim3(nb), dim3(256), 0, stream,
                       excl, blocksums, row_ptr, N, n_edges);
    hipLaunchKernelGGL(scatter_kernel, dim3(4096), dim3(256), 0, stream,
                       esrc, edst, ew, rank, row_ptr, meta, n_edges, nper);

    hipLaunchKernelGGL(cvtx_kernel, dim3(4096), dim3(256), 0, stream, x, x_bf, x_f8, N);

    hipLaunchKernelGGL(spmm512_kernel, dim3((N + 3) / 4), dim3(512), 0, stream,
                       row_ptr, meta, x_f8, Xa, N);

    dim3 blk(256);
    dim3 ggrid2((N + 127) / 128, 2);
    dim3 ogrid((N + 127) / 128);
    dim3 sgrid((N + 3) / 4);

    // ---- three input-layer GEMMs ----
    hipLaunchKernelGGL((gemm_lds_kernel<512, 512, false>), ggrid2, blk, 0, stream,
                       Xa, x_bf, (const float*)nullptr, Wf_in, b_in,
                       F0, stats + 0 * 1024, N);
    hipLaunchKernelGGL((gemm_lds_kernel<512, 512, false>), ggrid2, blk, 0, stream,
                       Xa, x_bf, (const float*)nullptr, Wf_in + (size_t)1 * 256 * 1024, b_in + 256,
                       G1, stats + 1 * 1024, N);
    hipLaunchKernelGGL((gemm_lds_kernel<512, 512, false>), ggrid2, blk, 0, stream,
                       Xa, x_bf, (const float*)nullptr, Wf_in + (size_t)2 * 256 * 1024, b_in + 512,
                       G2, stats + 2 * 1024, N);
    hipLaunchKernelGGL(bn_finalize3_kernel, dim3(3), dim3(256), 0, stream,
                       stats, g_in, be_in, N);

    float* kp0 = stats + 0 * 1024 + 512;
    float* kp1 = stats + 1 * 1024 + 512;
    float* kp2 = stats + 2 * 1024 + 512;
    float* st3 = stats + 3 * 1024;
    float* st4 = stats + 4 * 1024;
    float* st5 = stats + 5 * 1024;

    // ---- bn+relu fp8 interleave, then pure dual gather ----
    hipLaunchKernelGGL(bnrelu2_f8_kernel, dim3(2048), blk, 0, stream,
                       G1, kp1, G2, kp2, GG8, N);
    hipLaunchKernelGGL(spmm256x2_kernel, sgrid, blk, 0, stream,
                       row_ptr, meta, GG8, Ha, Ha2, N);

    // ---- j = 1: gemm -> F1 ----
    hipLaunchKernelGGL((gemm_lds_kernel<256, 256, true>), ggrid2, blk, 0, stream,
                       Ha, G1, kp1, Wf_h, b_h, F1, st3, N);
    hipLaunchKernelGGL(bn_finalize_kernel, dim3(1), dim3(256), 0, stream, st3, g_h, be_h, st3 + 512, N);

    // ---- j = 2: two hidden GCs ----
    hipLaunchKernelGGL((gemm_lds_kernel<256, 256, true>), ggrid2, blk, 0, stream,
                       Ha2, G2, kp2, Wf_h + (size_t)1 * 256 * 512, b_h + 256,
                       H2, st4, N);
    hipLaunchKernelGGL(bn_finalize_kernel, dim3(1), dim3(256), 0, stream, st4, g_h + 256, be_h + 256, st4 + 512, N);

    hipLaunchKernelGGL(bnrelu1_f8_kernel, dim3(2048), blk, 0, stream,
                       H2, st4 + 512, H28, N);
    hipLaunchKernelGGL(spmm256_kernel, sgrid, blk, 0, stream, row_ptr, meta, H28, Ha, N);
    hipLaunchKernelGGL((gemm_lds_kernel<256, 256, true>), ggrid2, blk, 0, stream,
                       Ha, H2, st4 + 512, Wf_h + (size_t)2 * 256 * 512, b_h + 512,
                       F2, st5, N);
    hipLaunchKernelGGL(bn_finalize_kernel, dim3(1), dim3(256), 0, stream, st5, g_h + 512, be_h + 512, st5 + 512, N);

    // ---- final outproj ----
    hipLaunchKernelGGL(outproj_mfma_kernel, ogrid, blk, 0, stream,
                       x_bf, F0, kp0, F1, st3 + 512, F2, st5 + 512,
                       Wcb, bc, out, N);
}